// Round 7
// baseline (503.961 us; speedup 1.0000x reference)
//
#include <hip/hip_runtime.h>
#include <hip/hip_bf16.h>
#include <cstdint>

// Problem constants (b=2, s=4096, dim=1024, heads=64, dim_head=64)
#define M_TOK 8192
#define DIM   1024
#define INNER 4096
#define HEADS 64
#define DH    64
#define QSCALE 0.125f      // 64^-0.5
#define EPS    1e-6f

typedef __hip_bfloat16 bf16;
typedef __bf16 bf16x8_t __attribute__((ext_vector_type(8)));
typedef float f32x4_t __attribute__((ext_vector_type(4)));

__device__ __forceinline__ float bfbits2f(unsigned short u) {
  return __uint_as_float(((unsigned)u) << 16);
}
__device__ __forceinline__ unsigned short f2bfbits(float f) {
  __hip_bfloat16 h = __float2bfloat16(f);
  unsigned short u;
  __builtin_memcpy(&u, &h, 2);
  return u;
}

// async global->LDS, 16B per lane. LDS dst must be wave-uniform base + lane*16.
__device__ __forceinline__ void load_lds16(const void* g, void* l) {
  __builtin_amdgcn_global_load_lds(
      (__attribute__((address_space(1))) void*)g,
      (__attribute__((address_space(3))) void*)l, 16, 0, 0);
}

__device__ __forceinline__ void asm_barrier() {
  asm volatile("s_barrier" ::: "memory");
}

// Counted lgkm wait + sched_barrier(0).  SB required (rule #18): hipcc hoists
// register-only MFMAs above inline-asm lgkmcnt despite the "memory" clobber.
#define LGKM_SB(N) do { \
    asm volatile("s_waitcnt lgkmcnt(" #N ")" ::: "memory"); \
    __builtin_amdgcn_sched_barrier(0); } while (0)

// XCD-aware block swizzle: XCD x owns M-tiles [x*gy/8, (x+1)*gy/8), N-major
// within the XCD.
__device__ __forceinline__ void swizzle_xy(int& bx, int& by) {
  const int gx = gridDim.x, gy = gridDim.y;
  const int id  = blockIdx.x + gx * blockIdx.y;
  const int per = gy >> 3;          // M-tiles per XCD (gy % 8 == 0)
  const int xcd = id & 7;
  const int s   = id >> 3;
  by = xcd * per + (s % per);
  bx = s / per;
}

// ---------------------------------------------------------------------------
// cast x (fp32) -> bf16, same layout. One float4 per thread.
// ---------------------------------------------------------------------------
__global__ __launch_bounds__(256) void castx_kernel(
    const float* __restrict__ x, unsigned short* __restrict__ xb, int n4)
{
  const int i = blockIdx.x * 256 + threadIdx.x;
  if (i < n4) {
    const float4 v = reinterpret_cast<const float4*>(x)[i];
    ushort4 o;
    o.x = f2bfbits(v.x); o.y = f2bfbits(v.y);
    o.z = f2bfbits(v.z); o.w = f2bfbits(v.w);
    reinterpret_cast<ushort4*>(xb)[i] = o;
  }
}

// ---------------------------------------------------------------------------
// transpose-cast: W [R][C] fp32 -> Wt [C][R] bf16.  32x32 LDS tiles.
// ---------------------------------------------------------------------------
__global__ __launch_bounds__(256) void tcast_kernel(
    const float* __restrict__ W, unsigned short* __restrict__ Wt, int R, int C)
{
  __shared__ float tile[32][33];
  const int bx = blockIdx.x * 32;   // C offset
  const int by = blockIdx.y * 32;   // R offset
  const int tx = threadIdx.x & 31;
  const int ty = threadIdx.x >> 5;  // 0..7
#pragma unroll
  for (int k = 0; k < 4; ++k)
    tile[ty + k * 8][tx] = W[(size_t)(by + ty + k * 8) * C + bx + tx];
  __syncthreads();
#pragma unroll
  for (int k = 0; k < 4; ++k)
    Wt[(size_t)(bx + ty + k * 8) * R + by + tx] = f2bfbits(tile[tx][ty + k * 8]);
}

// Dual version: z=0 -> W0 into Wt[0:C*R), z=1 -> W1 into Wt[C*R:2*C*R).
__global__ __launch_bounds__(256) void tcast_dual_kernel(
    const float* __restrict__ W0, const float* __restrict__ W1,
    unsigned short* __restrict__ Wt, int R, int C)
{
  __shared__ float tile[32][33];
  const float* W = blockIdx.z ? W1 : W0;
  unsigned short* dst = Wt + (size_t)blockIdx.z * R * C;
  const int bx = blockIdx.x * 32;
  const int by = blockIdx.y * 32;
  const int tx = threadIdx.x & 31;
  const int ty = threadIdx.x >> 5;
#pragma unroll
  for (int k = 0; k < 4; ++k)
    tile[ty + k * 8][tx] = W[(size_t)(by + ty + k * 8) * C + bx + tx];
  __syncthreads();
#pragma unroll
  for (int k = 0; k < 4; ++k)
    dst[(size_t)(bx + ty + k * 8) * R + by + tx] = f2bfbits(tile[tx][ty + k * 8]);
}

// ---------------------------------------------------------------------------
// 128x128 slip GEMM, BK=32, 256 thr = 4 waves (2M x 2N, 64x64 each).
// LDS 48 KB: As[3][128x32] + Bs[3][128x32] -> 3 blocks/CU co-resident.
//
// R7 FIX (single variable vs R6): TRIPLE-buffer rotation.  R6's same-buffer
// restage (stage T+2 into the buffer being read for T, guarded only by this
// wave's LGKM(0)) raced cross-wave at 3 blocks/CU: a fast wave's DMA could
// land before a contention-delayed wave issued its reads (absmax 0.25).
// Structural fix: tile T reads buf T%3; T+2 stages into buf (T+2)%3, which
// is neither T's nor T+1's buffer.  It overwrites tile T-1's buffer, and ALL
// waves' reads of T-1 retired before they passed the end-of-(T-1) barrier
// (each wave's own LGKM(0) precedes that barrier in program order) => WAR
// safety is barrier-enforced, not timing-enforced.
//
// LDS swizzle (BK=32: 4 chunks of 16B per row): slot = chunk ^ (r&3) ^
// ((r>>2)&3) — 2 lanes/bank-group max = free (m136).
//
// vmcnt ledger (4 loads/thread per tile: 2xA + 2xB):
//   prologue: stage T0, T1 (8 loads); vmcnt(4) -> T0 resident.
//   end of tile T: outstanding = T+1 (4, issued at T-1) + T+2 (4, issued
//   at T) = 8 -> vmcnt(4) retires exactly T+1.  Tail (T >= NT-2): vmcnt(0).
// MODE: 0 identity, 1 relu, 2 relu*QSCALE.  DUAL: split-N K/V epilogue.
// ---------------------------------------------------------------------------
__device__ __forceinline__ void stage32(
    const unsigned short* __restrict__ G, unsigned short* L,
    int rowbase, int k0, int K, int tid)
{
#pragma unroll
  for (int j = 0; j < 2; ++j) {
    const int q  = j * 256 + tid;   // chunk 0..511 of the 128x32 tile
    const int r  = q >> 2;          // row 0..127
    const int s  = q & 3;           // stored slot
    const int cg = s ^ (r & 3) ^ ((r >> 2) & 3);  // global k-chunk (inverse swz)
    load_lds16(&G[(size_t)(rowbase + r) * K + k0 + cg * 8], &L[q * 8]);
  }
}

template <int MODE, int DUAL>
__global__ __launch_bounds__(256, 3) void gemm128(
    const unsigned short* __restrict__ A,   // [M][K] bf16
    const unsigned short* __restrict__ Bt,  // [N][K] bf16 (B transposed)
    unsigned short* __restrict__ C0,
    unsigned short* __restrict__ C1,
    int N, int K)
{
  __shared__ __align__(16) unsigned short As[3][128 * 32];  // 8 KB each
  __shared__ __align__(16) unsigned short Bs[3][128 * 32];  // 48 KB total

  int bxi, byi;
  swizzle_xy(bxi, byi);
  const int tid  = threadIdx.x;
  const int bm   = byi * 128;
  const int bn   = bxi * 128;
  const int lane = tid & 63;
  const int w    = tid >> 6;
  const int wm   = (w & 1) * 64;
  const int wn   = (w >> 1) * 64;
  const int quad = lane >> 4;
  const int l15  = lane & 15;

  f32x4_t acc[4][4];
#pragma unroll
  for (int mt = 0; mt < 4; ++mt)
#pragma unroll
    for (int nt = 0; nt < 4; ++nt) acc[mt][nt] = (f32x4_t){0.f, 0.f, 0.f, 0.f};

  const int NT = K >> 5;

  // prologue: T0 -> buf0, T1 -> buf1; vmcnt(4) = T0 resident.
  stage32(A,  As[0], bm, 0,  K, tid);
  stage32(Bt, Bs[0], bn, 0,  K, tid);
  stage32(A,  As[1], bm, 32, K, tid);
  stage32(Bt, Bs[1], bn, 32, K, tid);
  asm volatile("s_waitcnt vmcnt(4)" ::: "memory");
  asm_barrier();
  __builtin_amdgcn_sched_barrier(0);

  bf16x8_t af[4], bfr[4];

  int c = 0;           // buffer of tile T
  int cs = 2;          // buffer for tile T+2 staging ((T+2)%3)
  for (int T = 0; T < NT; ++T) {
    const unsigned short* Ac = As[c];
    const unsigned short* Bc = Bs[c];
    const bool pA = (T + 2 < NT);
    const int kN = (T + 2) * 32;

#pragma unroll
    for (int mt = 0; mt < 4; ++mt) {
      const int r = wm + mt * 16 + l15;
      const int s = quad ^ (r & 3) ^ ((r >> 2) & 3);
      af[mt] = *reinterpret_cast<const bf16x8_t*>(&Ac[r * 32 + s * 8]);
    }
#pragma unroll
    for (int nt = 0; nt < 4; ++nt) {
      const int r = wn + nt * 16 + l15;
      const int s = quad ^ (r & 3) ^ ((r >> 2) & 3);
      bfr[nt] = *reinterpret_cast<const bf16x8_t*>(&Bc[r * 32 + s * 8]);
    }
    LGKM_SB(0);                       // own reads retired (precedes barrier)
    if (pA) {
      stage32(A,  As[cs], bm, kN, K, tid);   // (T+2)%3: not T's, not T+1's buf
      stage32(Bt, Bs[cs], bn, kN, K, tid);
    }
    __builtin_amdgcn_s_setprio(1);
#pragma unroll
    for (int mt = 0; mt < 4; ++mt)
#pragma unroll
      for (int nt = 0; nt < 4; ++nt)
        acc[mt][nt] = __builtin_amdgcn_mfma_f32_16x16x32_bf16(
            af[mt], bfr[nt], acc[mt][nt], 0, 0, 0);
    __builtin_amdgcn_s_setprio(0);
    if (T < NT - 2) {
      asm volatile("s_waitcnt vmcnt(4)" ::: "memory");  // T+1 resident
    } else {
      asm volatile("s_waitcnt vmcnt(0)" ::: "memory");  // tail drain
    }
    asm_barrier();
    __builtin_amdgcn_sched_barrier(0);
    c  = (c  == 2) ? 0 : c + 1;
    cs = (cs == 2) ? 0 : cs + 1;
  }

  // ---- epilogue ----
  if (DUAL) {
    const bool isK = (bn < 4096);
    unsigned short* __restrict__ C = isK ? C0 : C1;
    const int bnc = bn & 4095;
#pragma unroll
    for (int mt = 0; mt < 4; ++mt)
#pragma unroll
      for (int i = 0; i < 4; ++i) {
        const size_t rowg = (size_t)(bm + wm + mt * 16 + quad * 4 + i);
#pragma unroll
        for (int nt = 0; nt < 4; ++nt) {
          float v = acc[mt][nt][i];
          if (isK) v = fmaxf(v, 0.f);
          C[rowg * 4096 + bnc + wn + nt * 16 + l15] = f2bfbits(v);
        }
      }
  } else {
#pragma unroll
    for (int mt = 0; mt < 4; ++mt)
#pragma unroll
      for (int i = 0; i < 4; ++i) {
        const size_t rowg = (size_t)(bm + wm + mt * 16 + quad * 4 + i);
#pragma unroll
        for (int nt = 0; nt < 4; ++nt) {
          float v = acc[mt][nt][i];
          if (MODE >= 1) v = fmaxf(v, 0.f);
          if (MODE == 2) v *= QSCALE;
          C0[rowg * (size_t)N + bn + wn + nt * 16 + l15] = f2bfbits(v);
        }
      }
  }
}

// ---------------------------------------------------------------------------
// Output GEMM, same 128x128/BK=32 triple-buffer slip structure, fp32 out.
// ---------------------------------------------------------------------------
__global__ __launch_bounds__(256, 3) void gemm_out128(
    const unsigned short* __restrict__ A,   // [M][K] bf16
    const unsigned short* __restrict__ Bt,  // [N][K] bf16
    const float* __restrict__ bias,
    float* __restrict__ out, int N, int K)
{
  __shared__ __align__(16) unsigned short As[3][128 * 32];
  __shared__ __align__(16) unsigned short Bs[3][128 * 32];

  int bxi, byi;
  swizzle_xy(bxi, byi);
  const int tid  = threadIdx.x;
  const int bm   = byi * 128;
  const int bn   = bxi * 128;
  const int lane = tid & 63;
  const int w    = tid >> 6;
  const int wm   = (w & 1) * 64;
  const int wn   = (w >> 1) * 64;
  const int quad = lane >> 4;
  const int l15  = lane & 15;

  f32x4_t acc[4][4];
#pragma unroll
  for (int mt = 0; mt < 4; ++mt)
#pragma unroll
    for (int nt = 0; nt < 4; ++nt) acc[mt][nt] = (f32x4_t){0.f, 0.f, 0.f, 0.f};

  const int NT = K >> 5;

  stage32(A,  As[0], bm, 0,  K, tid);
  stage32(Bt, Bs[0], bn, 0,  K, tid);
  stage32(A,  As[1], bm, 32, K, tid);
  stage32(Bt, Bs[1], bn, 32, K, tid);
  asm volatile("s_waitcnt vmcnt(4)" ::: "memory");
  asm_barrier();
  __builtin_amdgcn_sched_barrier(0);

  bf16x8_t af[4], bfr[4];

  int c = 0, cs = 2;
  for (int T = 0; T < NT; ++T) {
    const unsigned short* Ac = As[c];
    const unsigned short* Bc = Bs[c];
    const bool pA = (T + 2 < NT);
    const int kN = (T + 2) * 32;

#pragma unroll
    for (int mt = 0; mt < 4; ++mt) {
      const int r = wm + mt * 16 + l15;
      const int s = quad ^ (r & 3) ^ ((r >> 2) & 3);
      af[mt] = *reinterpret_cast<const bf16x8_t*>(&Ac[r * 32 + s * 8]);
    }
#pragma unroll
    for (int nt = 0; nt < 4; ++nt) {
      const int r = wn + nt * 16 + l15;
      const int s = quad ^ (r & 3) ^ ((r >> 2) & 3);
      bfr[nt] = *reinterpret_cast<const bf16x8_t*>(&Bc[r * 32 + s * 8]);
    }
    LGKM_SB(0);
    if (pA) {
      stage32(A,  As[cs], bm, kN, K, tid);
      stage32(Bt, Bs[cs], bn, kN, K, tid);
    }
    __builtin_amdgcn_s_setprio(1);
#pragma unroll
    for (int mt = 0; mt < 4; ++mt)
#pragma unroll
      for (int nt = 0; nt < 4; ++nt)
        acc[mt][nt] = __builtin_amdgcn_mfma_f32_16x16x32_bf16(
            af[mt], bfr[nt], acc[mt][nt], 0, 0, 0);
    __builtin_amdgcn_s_setprio(0);
    if (T < NT - 2) {
      asm volatile("s_waitcnt vmcnt(4)" ::: "memory");
    } else {
      asm volatile("s_waitcnt vmcnt(0)" ::: "memory");
    }
    asm_barrier();
    __builtin_amdgcn_sched_barrier(0);
    c  = (c  == 2) ? 0 : c + 1;
    cs = (cs == 2) ? 0 : cs + 1;
  }

#pragma unroll
  for (int mt = 0; mt < 4; ++mt)
#pragma unroll
    for (int i = 0; i < 4; ++i) {
      const size_t rowg = (size_t)(bm + wm + mt * 16 + quad * 4 + i);
#pragma unroll
      for (int nt = 0; nt < 4; ++nt) {
        const int colg = bn + wn + nt * 16 + l15;
        out[rowg * N + colg] = acc[mt][nt][i] + bias[colg];
      }
    }
}

// ---------------------------------------------------------------------------
// ksum[t][d] = sum_i K[t][i*64+d].  One wave per token, 4 tokens/block.
// ---------------------------------------------------------------------------
__global__ __launch_bounds__(256) void ksum_kernel(
    const unsigned short* __restrict__ Kb, float* __restrict__ ks)
{
  const int t = blockIdx.x * 4 + (threadIdx.x >> 6);
  const int j = threadIdx.x & 63;
  const uint4* row = reinterpret_cast<const uint4*>(Kb + (size_t)t * INNER);
  float s[8] = {0.f, 0.f, 0.f, 0.f, 0.f, 0.f, 0.f, 0.f};
#pragma unroll
  for (int m = 0; m < 8; ++m) {
    const uint4 u = row[j + 64 * m];
    s[0] += __uint_as_float((u.x & 0xFFFFu) << 16);
    s[1] += __uint_as_float(u.x & 0xFFFF0000u);
    s[2] += __uint_as_float((u.y & 0xFFFFu) << 16);
    s[3] += __uint_as_float(u.y & 0xFFFF0000u);
    s[4] += __uint_as_float((u.z & 0xFFFFu) << 16);
    s[5] += __uint_as_float(u.z & 0xFFFF0000u);
    s[6] += __uint_as_float((u.w & 0xFFFFu) << 16);
    s[7] += __uint_as_float(u.w & 0xFFFF0000u);
  }
#pragma unroll
  for (int off = 8; off < 64; off <<= 1)
#pragma unroll
    for (int e = 0; e < 8; ++e) s[e] += __shfl_xor(s[e], off, 64);
  if (j < 8) {
    float4* dst = reinterpret_cast<float4*>(ks + t * 64 + j * 8);
    float4 lo, hi;
    lo.x = s[0]; lo.y = s[1]; lo.z = s[2]; lo.w = s[3];
    hi.x = s[4]; hi.y = s[5]; hi.z = s[6]; hi.w = s[7];
    dst[0] = lo; dst[1] = hi;
  }
}

// ---------------------------------------------------------------------------
// MFMA attention: one wave per token, 4 tokens/block, zero LDS.
// ---------------------------------------------------------------------------
__global__ __launch_bounds__(256) void attn_mfma(
    const unsigned short* __restrict__ Qb, const unsigned short* __restrict__ Vb,
    const float* __restrict__ ksum, unsigned short* __restrict__ Ab)
{
  const int t    = blockIdx.x * 4 + (threadIdx.x >> 6);
  const int lane = threadIdx.x & 63;
  const int l15  = lane & 15;
  const int quad = lane >> 4;
  const size_t base = (size_t)t * INNER;

  union VU { bf16x8_t v; unsigned short u[8]; };

  float ksv[2][8];
#pragma unroll
  for (int kt = 0; kt < 2; ++kt) {
    const float4* p = reinterpret_cast<const float4*>(ksum + t * 64 + kt * 32 + quad * 8);
    const float4 a = p[0], b = p[1];
    ksv[kt][0] = a.x; ksv[kt][1] = a.y; ksv[kt][2] = a.z; ksv[kt][3] = a.w;
    ksv[kt][4] = b.x; ksv[kt][5] = b.y; ksv[kt][6] = b.z; ksv[kt][7] = b.w;
  }

  bf16x8_t vs[4][2];
#pragma unroll
  for (int nt = 0; nt < 4; ++nt)
#pragma unroll
    for (int kt = 0; kt < 2; ++kt) {
      VU vr, vo;
      vr.v = *reinterpret_cast<const bf16x8_t*>(
          Vb + base + (size_t)(nt * 16 + l15) * 64 + kt * 32 + quad * 8);
#pragma unroll
      for (int j = 0; j < 8; ++j)
        vo.u[j] = f2bfbits(bfbits2f(vr.u[j]) * ksv[kt][j]);
      vs[nt][kt] = vo.v;
    }

  bf16x8_t qf[4][2];
  float qn[4] = {0.f, 0.f, 0.f, 0.f};
#pragma unroll
  for (int mt = 0; mt < 4; ++mt)
#pragma unroll
    for (int kt = 0; kt < 2; ++kt) {
      VU qr;
      qr.v = *reinterpret_cast<const bf16x8_t*>(
          Qb + base + (size_t)(mt * 16 + l15) * 64 + kt * 32 + quad * 8);
      qf[mt][kt] = qr.v;
#pragma unroll
      for (int j = 0; j < 8; ++j)
        qn[mt] += bfbits2f(qr.u[j]) * ksv[kt][j];
    }
#pragma unroll
  for (int mt = 0; mt < 4; ++mt) {
    qn[mt] += __shfl_xor(qn[mt], 16, 64);
    qn[mt] += __shfl_xor(qn[mt], 32, 64);
  }

  f32x4_t acc[4][4];
#pragma unroll
  for (int mt = 0; mt < 4; ++mt)
#pragma unroll
    for (int nt = 0; nt < 4; ++nt) acc[mt][nt] = (f32x4_t){0.f, 0.f, 0.f, 0.f};

#pragma unroll
  for (int mt = 0; mt < 4; ++mt)
#pragma unroll
    for (int nt = 0; nt < 4; ++nt) {
      acc[mt][nt] = __builtin_amdgcn_mfma_f32_16x16x32_bf16(
          qf[mt][0], vs[nt][0], acc[mt][nt], 0, 0, 0);
      acc[mt][nt] = __builtin_amdgcn_mfma_f32_16x16x32_bf16(
          qf[mt][1], vs[nt][1], acc[mt][nt], 0, 0, 0);
    }

#pragma unroll
  for (int mt = 0; mt < 4; ++mt)
#pragma unroll
    for (int i = 0; i < 4; ++i) {
      const float inv = 1.f / (__shfl(qn[mt], quad * 4 + i, 64) + EPS);
      const size_t roff = base + (size_t)(mt * 16 + quad * 4 + i) * 64;
#pragma unroll
      for (int nt = 0; nt < 4; ++nt)
        Ab[roff + nt * 16 + l15] = f2bfbits(acc[mt][nt][i] * inv);
    }
}

// ---------------------------------------------------------------------------
// Buffers (ws = 130 MB):
//  ws   @0      : K (transient) -> Q -> A (in place)
//  ws   @64MB   : V ; first 8MB reused for Wo^T after attn
//  ws   @128MB  : ksum (fp32 8192x64, 2MB)
//  d_out@0      : Xb (bf16 8192x1024, 16MB)       — dead before gemm_out writes
//  d_out@16MB   : WtKV (bf16 8192x1024, 16MB)     — then WqT (8MB)
// ---------------------------------------------------------------------------
extern "C" void kernel_launch(void* const* d_in, const int* in_sizes, int n_in,
                              void* d_out, int out_size, void* d_ws, size_t ws_size,
                              hipStream_t stream)
{
  const float* x  = (const float*)d_in[0];
  const float* Wq = (const float*)d_in[1];
  const float* Wk = (const float*)d_in[2];
  const float* Wv = (const float*)d_in[3];
  const float* Wo = (const float*)d_in[4];
  const float* bo = (const float*)d_in[5];
  float* out = (float*)d_out;

  uint8_t* ws = (uint8_t*)d_ws;
  const size_t HALF = (size_t)M_TOK * INNER * sizeof(bf16);  // 64 MB
  unsigned short* KQA = (unsigned short*)ws;            // K -> Q -> A
  unsigned short* Vb  = (unsigned short*)(ws + HALF);   // V ; then Wo^T
  float* ks           = (float*)(ws + 2 * HALF);

  unsigned short* Xb   = (unsigned short*)d_out;                           // 16 MB
  unsigned short* WtKV = (unsigned short*)((uint8_t*)d_out + (16u << 20)); // 16 MB
  unsigned short* WqT  = WtKV;   // reused after gemm_kv
  unsigned short* Wot  = Vb;     // Wo^T over dead V (after attn)

  const dim3 blk(256);

  castx_kernel<<<dim3(M_TOK * DIM / 4 / 256), blk, 0, stream>>>(
      x, Xb, M_TOK * DIM / 4);

  // Wk^T and Wv^T stacked -> WtKV [8192][1024]
  tcast_dual_kernel<<<dim3(INNER / 32, DIM / 32, 2), blk, 0, stream>>>(
      Wk, Wv, WtKV, DIM, INNER);

  // fused K+V projection: 128^2 triple-buffer slip, 3 blocks/CU, DUAL epilogue
  gemm128<0, 1><<<dim3(2 * INNER / 128, M_TOK / 128), blk, 0, stream>>>(
      Xb, WtKV, KQA, Vb, 2 * INNER, DIM);

  ksum_kernel<<<dim3(M_TOK / 4), blk, 0, stream>>>(KQA, ks);

  tcast_kernel<<<dim3(INNER / 32, DIM / 32), blk, 0, stream>>>(
      Wq, WqT, DIM, INNER);

  // Q projection: relu * QSCALE, overwrites dead K
  gemm128<2, 0><<<dim3(INNER / 128, M_TOK / 128), blk, 0, stream>>>(
      Xb, WqT, KQA, nullptr, INNER, DIM);

  attn_mfma<<<dim3(M_TOK / 4), blk, 0, stream>>>(KQA, Vb, ks, KQA);  // A in place

  tcast_kernel<<<dim3(DIM / 32, INNER / 32), blk, 0, stream>>>(
      Wo, Wot, INNER, DIM);  // over dead V

  gemm_out128<<<dim3(DIM / 128, M_TOK / 128), blk, 0, stream>>>(
      KQA, Wot, bo, out, DIM, INNER);
}

// Round 8
// 484.812 us; speedup vs baseline: 1.0395x; 1.0395x over previous
//
#include <hip/hip_runtime.h>
#include <hip/hip_bf16.h>
#include <cstdint>

// Problem constants (b=2, s=4096, dim=1024, heads=64, dim_head=64)
#define M_TOK 8192
#define DIM   1024
#define INNER 4096
#define HEADS 64
#define DH    64
#define QSCALE 0.125f      // 64^-0.5
#define EPS    1e-6f

typedef __hip_bfloat16 bf16;
typedef __bf16 bf16x8_t __attribute__((ext_vector_type(8)));
typedef float f32x4_t __attribute__((ext_vector_type(4)));

__device__ __forceinline__ float bfbits2f(unsigned short u) {
  return __uint_as_float(((unsigned)u) << 16);
}
__device__ __forceinline__ unsigned short f2bfbits(float f) {
  __hip_bfloat16 h = __float2bfloat16(f);
  unsigned short u;
  __builtin_memcpy(&u, &h, 2);
  return u;
}

// async global->LDS, 16B per lane. LDS dst must be wave-uniform base + lane*16.
__device__ __forceinline__ void load_lds16(const void* g, void* l) {
  __builtin_amdgcn_global_load_lds(
      (__attribute__((address_space(1))) void*)g,
      (__attribute__((address_space(3))) void*)l, 16, 0, 0);
}

__device__ __forceinline__ void asm_barrier() {
  asm volatile("s_barrier" ::: "memory");
}

// Counted lgkm wait + sched_barrier(0).  SB required (rule #18): hipcc hoists
// register-only MFMAs above inline-asm lgkmcnt despite the "memory" clobber.
#define LGKM_SB(N) do { \
    asm volatile("s_waitcnt lgkmcnt(" #N ")" ::: "memory"); \
    __builtin_amdgcn_sched_barrier(0); } while (0)

// XCD-aware block swizzle: XCD x owns M-tiles [x*gy/8, (x+1)*gy/8), N-major
// within the XCD.
__device__ __forceinline__ void swizzle_xy(int& bx, int& by) {
  const int gx = gridDim.x, gy = gridDim.y;
  const int id  = blockIdx.x + gx * blockIdx.y;
  const int per = gy >> 3;          // M-tiles per XCD (gy % 8 == 0)
  const int xcd = id & 7;
  const int s   = id >> 3;
  by = xcd * per + (s % per);
  bx = s / per;
}

// ---------------------------------------------------------------------------
// Fused prep kernel (R8): castx + Wk^T + Wv^T in ONE launch.
//   blocks [0, 8192)        : cast x fp32 -> bf16 (one float4/thread)
//   blocks [8192, 12288)    : transpose-cast Wk -> WtKV[0:4096*1024)
//   blocks [12288, 16384)   : transpose-cast Wv -> WtKV[4096*1024:...)
// Wq^T CANNOT join: it would overwrite WtKV, which gemm_kv still reads.
// Math of each role is identical to the verified castx/tcast_dual kernels.
// ---------------------------------------------------------------------------
__global__ __launch_bounds__(256) void prep_kernel(
    const float* __restrict__ x, unsigned short* __restrict__ xb,
    const float* __restrict__ Wk, const float* __restrict__ Wv,
    unsigned short* __restrict__ WtKV)
{
  const int bid = blockIdx.x;
  if (bid < 8192) {
    const int i = bid * 256 + threadIdx.x;   // exactly 8192*256 float4s
    const float4 v = reinterpret_cast<const float4*>(x)[i];
    ushort4 o;
    o.x = f2bfbits(v.x); o.y = f2bfbits(v.y);
    o.z = f2bfbits(v.z); o.w = f2bfbits(v.w);
    reinterpret_cast<ushort4*>(xb)[i] = o;
    return;
  }
  // transpose-cast role: W [1024][4096] -> Wt [4096][1024], 32x32 tiles
  __shared__ float tile[32][33];
  const int t    = bid - 8192;
  const int z    = t >> 12;               // 0 = Wk, 1 = Wv (4096 tiles each)
  const int tt   = t & 4095;
  const float* W = z ? Wv : Wk;
  unsigned short* dst = WtKV + (size_t)z * DIM * INNER;
  const int bx = (tt & 127) * 32;         // C offset (C = 4096 -> 128 tiles)
  const int by = (tt >> 7) * 32;          // R offset (R = 1024 -> 32 tiles)
  const int tx = threadIdx.x & 31;
  const int ty = threadIdx.x >> 5;        // 0..7
#pragma unroll
  for (int k = 0; k < 4; ++k)
    tile[ty + k * 8][tx] = W[(size_t)(by + ty + k * 8) * INNER + bx + tx];
  __syncthreads();
#pragma unroll
  for (int k = 0; k < 4; ++k)
    dst[(size_t)(bx + ty + k * 8) * DIM + by + tx] = f2bfbits(tile[tx][ty + k * 8]);
}

// ---------------------------------------------------------------------------
// transpose-cast: W [R][C] fp32 -> Wt [C][R] bf16.  32x32 LDS tiles.
// (kept for Wq^T and Wo^T, whose destinations are not free at prep time)
// ---------------------------------------------------------------------------
__global__ __launch_bounds__(256) void tcast_kernel(
    const float* __restrict__ W, unsigned short* __restrict__ Wt, int R, int C)
{
  __shared__ float tile[32][33];
  const int bx = blockIdx.x * 32;   // C offset
  const int by = blockIdx.y * 32;   // R offset
  const int tx = threadIdx.x & 31;
  const int ty = threadIdx.x >> 5;  // 0..7
#pragma unroll
  for (int k = 0; k < 4; ++k)
    tile[ty + k * 8][tx] = W[(size_t)(by + ty + k * 8) * C + bx + tx];
  __syncthreads();
#pragma unroll
  for (int k = 0; k < 4; ++k)
    Wt[(size_t)(bx + ty + k * 8) * R + by + tx] = f2bfbits(tile[tx][ty + k * 8]);
}

// ---------------------------------------------------------------------------
// 256x256 slip-pipelined GEMM (R5-VERIFIED — do not modify).  512 thr =
// 8 waves (2M x 4N), BK=64.  LDS 128 KB: As[2][256x64] + Bs[2][256x64].
// Swizzle: slot = chunk^(row&7) (conflict-free, SQ_LDS_BANK_CONFLICT == 0).
//
// Schedule: ONE barrier per K-tile + counted lgkmcnt so each quadrant's MFMA
// overlaps the next quadrant's ds_read delivery:
//   [seam, prev iter] read af0-3,bfr0-1 of T   (12 ds_reads)
//   top:  read af4-7 (8); LGKM(8); MFMA q0
//         read bfr2-3 (4); stage B.h0(T+1); LGKM(4); MFMA q1
//         stage B.h1(T+1); stage A.h0(T+2); LGKM(0); MFMA q2
//         stage A.h1(T+2); MFMA q3
//         vmcnt(4) [tail: 0]; s_barrier; seam reads for T+1
// vmcnt ledger at tile end: outstanding oldest-first = T+1.B(4), T+2.A(4)
// plus T+1.A retired -> vmcnt(4) => tile T+1 resident, T+2.A in flight.
// WAR on As[c] (A of T+2 lands in the buffer read this tile): all As[c]
// reads retire at LGKM(8)/LGKM(4), >= 2 MFMA clusters + flight before the
// DMA lands; validated at 1 block/CU (R5, absmax 0.0078).
// MODE: 0 identity, 1 relu, 2 relu*QSCALE.  DUAL: split-N K/V epilogue.
// ---------------------------------------------------------------------------
__device__ __forceinline__ void stage_half(
    const unsigned short* __restrict__ G, unsigned short* L,
    int rowbase, int k0, int K, int h, int tid)
{
#pragma unroll
  for (int j = 0; j < 2; ++j) {
    const int q  = h * 1024 + j * 512 + tid;     // chunk index in 256x64 tile
    const int r  = q >> 3;                       // row 0..255
    const int cg = (tid & 7) ^ (r & 7);          // global k-chunk (inverse swz)
    load_lds16(&G[(size_t)(rowbase + r) * K + k0 + cg * 8], &L[q * 8]);
  }
}

__device__ __forceinline__ void read_af4(
    const unsigned short* __restrict__ Ac, bf16x8_t (&af)[8][2],
    int m0, int wm, int l15, int quad)
{
#pragma unroll
  for (int mt = 0; mt < 4; ++mt) {
    const int r = wm + (m0 + mt) * 16 + l15;
#pragma unroll
    for (int kt = 0; kt < 2; ++kt) {
      const int s = (kt * 4 + quad) ^ (r & 7);
      af[m0 + mt][kt] = *reinterpret_cast<const bf16x8_t*>(&Ac[r * 64 + s * 8]);
    }
  }
}

__device__ __forceinline__ void read_bf2(
    const unsigned short* __restrict__ Bc, bf16x8_t (&bfr)[4][2],
    int n0, int wn, int l15, int quad)
{
#pragma unroll
  for (int nt = 0; nt < 2; ++nt) {
    const int r = wn + (n0 + nt) * 16 + l15;
#pragma unroll
    for (int kt = 0; kt < 2; ++kt) {
      const int s = (kt * 4 + quad) ^ (r & 7);
      bfr[n0 + nt][kt] = *reinterpret_cast<const bf16x8_t*>(&Bc[r * 64 + s * 8]);
    }
  }
}

__device__ __forceinline__ void mfma_quad(
    f32x4_t (&acc)[8][4], const bf16x8_t (&af)[8][2],
    const bf16x8_t (&bfr)[4][2], int m0, int n0)
{
  __builtin_amdgcn_s_setprio(1);
#pragma unroll
  for (int mt = m0; mt < m0 + 4; ++mt)
#pragma unroll
    for (int nt = n0; nt < n0 + 2; ++nt) {
      acc[mt][nt] = __builtin_amdgcn_mfma_f32_16x16x32_bf16(
          af[mt][0], bfr[nt][0], acc[mt][nt], 0, 0, 0);
      acc[mt][nt] = __builtin_amdgcn_mfma_f32_16x16x32_bf16(
          af[mt][1], bfr[nt][1], acc[mt][nt], 0, 0, 0);
    }
  __builtin_amdgcn_s_setprio(0);
}

template <int MODE, int DUAL>
__global__ __launch_bounds__(512, 2) void gemm256(
    const unsigned short* __restrict__ A,   // [M][K] bf16
    const unsigned short* __restrict__ Bt,  // [N][K] bf16 (B transposed)
    unsigned short* __restrict__ C0,
    unsigned short* __restrict__ C1,
    int N, int K)
{
  __shared__ __align__(16) unsigned short As[2][256 * 64];  // 64 KB
  __shared__ __align__(16) unsigned short Bs[2][256 * 64];  // 64 KB

  int bxi, byi;
  swizzle_xy(bxi, byi);
  const int tid  = threadIdx.x;
  const int bm   = byi * 256;
  const int bn   = bxi * 256;
  const int lane = tid & 63;
  const int w    = tid >> 6;
  const int wm   = (w >> 2) * 128;   // wave M offset (0/128)
  const int wn   = (w & 3) * 64;     // wave N offset (0/64/128/192)
  const int quad = lane >> 4;
  const int l15  = lane & 15;

  f32x4_t acc[8][4];
#pragma unroll
  for (int mt = 0; mt < 8; ++mt)
#pragma unroll
    for (int nt = 0; nt < 4; ++nt) acc[mt][nt] = (f32x4_t){0.f, 0.f, 0.f, 0.f};

  const int NT = K >> 6;

  bf16x8_t af[8][2], bfr[4][2];

  // ---- prologue: tile0 A+B, tile1 A staged; tile0 resident; seam reads ----
  stage_half(A,  As[0], bm, 0,  K, 0, tid);
  stage_half(A,  As[0], bm, 0,  K, 1, tid);
  stage_half(Bt, Bs[0], bn, 0,  K, 0, tid);
  stage_half(Bt, Bs[0], bn, 0,  K, 1, tid);
  stage_half(A,  As[1], bm, 64, K, 0, tid);
  stage_half(A,  As[1], bm, 64, K, 1, tid);
  asm volatile("s_waitcnt vmcnt(4)" ::: "memory");  // tile0 resident; tile1.A in flight
  asm_barrier();
  __builtin_amdgcn_sched_barrier(0);
  read_af4(As[0], af, 0, wm, l15, quad);   // seam for T=0: af0-3
  read_bf2(Bs[0], bfr, 0, wn, l15, quad);  //               bfr0-1

  for (int T = 0; T < NT; ++T) {
    const int c = T & 1;
    const unsigned short* Ac = As[c];
    const unsigned short* Bc = Bs[c];
    unsigned short* Bnx = Bs[c ^ 1];   // tile T+1 B lands here
    unsigned short* Anx = As[c];       // tile T+2 A lands here
    const int kB = (T + 1) * 64;
    const int kA = (T + 2) * 64;
    const bool pB = (T + 1 < NT);
    const bool pA = (T + 2 < NT);

    // region 1: issue q1 frags; wait seam; MFMA q0 overlaps af4-7 delivery
    read_af4(Ac, af, 4, wm, l15, quad);                 // 8 ds_reads
    LGKM_SB(8);                                         // seam (12) retired
    mfma_quad(acc, af, bfr, 0, 0);                      // q0: m0-3 x n0-1

    // region 2: issue q2 frags + B-stage; wait af4-7; MFMA q1 overlaps
    read_bf2(Bc, bfr, 2, wn, l15, quad);                // 4 ds_reads
    if (pB) stage_half(Bt, Bnx, bn, kB, K, 0, tid);
    LGKM_SB(4);                                         // af4-7 retired
    mfma_quad(acc, af, bfr, 4, 0);                      // q1: m4-7 x n0-1

    // region 3: stages; wait bfr2-3; MFMA q2
    if (pB) stage_half(Bt, Bnx, bn, kB, K, 1, tid);
    if (pA) stage_half(A, Anx, bm, kA, K, 0, tid);      // all As[c] reads retired
    LGKM_SB(0);                                         // bfr2-3 retired
    mfma_quad(acc, af, bfr, 0, 2);                      // q2: m0-3 x n2-3

    // region 4: last stage; MFMA q3; tile-boundary handoff
    if (pA) stage_half(A, Anx, bm, kA, K, 1, tid);
    mfma_quad(acc, af, bfr, 4, 2);                      // q3: m4-7 x n2-3
    if (T < NT - 2) {
      asm volatile("s_waitcnt vmcnt(4)" ::: "memory");  // T+1 resident; T+2.A in flight
    } else {
      asm volatile("s_waitcnt vmcnt(0)" ::: "memory");  // tail drain
    }
    asm_barrier();
    __builtin_amdgcn_sched_barrier(0);
    if (T + 1 < NT) {                                   // seam reads for T+1
      read_af4(As[c ^ 1], af, 0, wm, l15, quad);        // af0-3 (8)
      read_bf2(Bs[c ^ 1], bfr, 0, wn, l15, quad);       // bfr0-1 (4)
    }
  }

  // ---- epilogue ----
  if (DUAL) {
    const bool isK = (bn < 4096);
    unsigned short* __restrict__ C = isK ? C0 : C1;
    const int bnc = bn & 4095;
#pragma unroll
    for (int mt = 0; mt < 8; ++mt)
#pragma unroll
      for (int i = 0; i < 4; ++i) {
        const size_t rowg = (size_t)(bm + wm + mt * 16 + quad * 4 + i);
#pragma unroll
        for (int nt = 0; nt < 4; ++nt) {
          float v = acc[mt][nt][i];
          if (isK) v = fmaxf(v, 0.f);
          C[rowg * 4096 + bnc + wn + nt * 16 + l15] = f2bfbits(v);
        }
      }
  } else {
#pragma unroll
    for (int mt = 0; mt < 8; ++mt)
#pragma unroll
      for (int i = 0; i < 4; ++i) {
        const size_t rowg = (size_t)(bm + wm + mt * 16 + quad * 4 + i);
#pragma unroll
        for (int nt = 0; nt < 4; ++nt) {
          float v = acc[mt][nt][i];
          if (MODE >= 1) v = fmaxf(v, 0.f);
          if (MODE == 2) v *= QSCALE;
          C0[rowg * (size_t)N + bn + wn + nt * 16 + l15] = f2bfbits(v);
        }
      }
  }
}

// ---------------------------------------------------------------------------
// Output MFMA GEMM: out[M,N] = A[M,K] @ Bt[N,K]^T + bias[N], fp32 out.
// 128(M) x 64(N) tile, BK=64 (R5-verified structure).  N=1024 too narrow
// for 256^2 tiles (128 blocks would idle half the chip).
// ---------------------------------------------------------------------------
__global__ __launch_bounds__(256) void gemm_out_bf16(
    const unsigned short* __restrict__ A,   // [M][K] bf16
    const unsigned short* __restrict__ Bt,  // [N][K] bf16
    const float* __restrict__ bias,
    float* __restrict__ out, int M, int N, int K)
{
  __shared__ __align__(16) unsigned short As[128 * 64];  // 16 KB
  __shared__ __align__(16) unsigned short Bs[64 * 64];   //  8 KB

  int bxi, byi;
  swizzle_xy(bxi, byi);
  const int tid  = threadIdx.x;
  const int bm   = byi * 128;
  const int bn   = bxi * 64;
  const int lane = tid & 63;
  const int w    = tid >> 6;
  const int wm   = (w & 1) * 64;
  const int wn   = (w >> 1) * 32;
  const int quad = lane >> 4;
  const int l15  = lane & 15;

  f32x4_t acc[4][2];
#pragma unroll
  for (int mt = 0; mt < 4; ++mt)
#pragma unroll
    for (int nt = 0; nt < 2; ++nt) acc[mt][nt] = (f32x4_t){0.f, 0.f, 0.f, 0.f};

  int qa[4], ra[4], ca[4];
#pragma unroll
  for (int j = 0; j < 4; ++j) {
    qa[j] = tid + 256 * j;
    ra[j] = qa[j] >> 3;
    ca[j] = (qa[j] & 7) ^ (ra[j] & 7);
  }
  int qb[2], rb[2], cb[2];
#pragma unroll
  for (int j = 0; j < 2; ++j) {
    qb[j] = tid + 256 * j;
    rb[j] = qb[j] >> 3;
    cb[j] = (qb[j] & 7) ^ (rb[j] & 7);
  }

  for (int k0 = 0; k0 < K; k0 += 64) {
    __syncthreads();
#pragma unroll
    for (int j = 0; j < 4; ++j)
      load_lds16(&A[(size_t)(bm + ra[j]) * K + k0 + ca[j] * 8], &As[qa[j] * 8]);
#pragma unroll
    for (int j = 0; j < 2; ++j)
      load_lds16(&Bt[(size_t)(bn + rb[j]) * K + k0 + cb[j] * 8], &Bs[qb[j] * 8]);
    __syncthreads();

    bf16x8_t af[4][2], bfr[2][2];
#pragma unroll
    for (int mt = 0; mt < 4; ++mt) {
      const int r = wm + mt * 16 + l15;
#pragma unroll
      for (int kt = 0; kt < 2; ++kt) {
        const int slot = (kt * 4 + quad) ^ (r & 7);
        af[mt][kt] = *reinterpret_cast<const bf16x8_t*>(&As[r * 64 + slot * 8]);
      }
    }
#pragma unroll
    for (int nt = 0; nt < 2; ++nt) {
      const int r = wn + nt * 16 + l15;
#pragma unroll
      for (int kt = 0; kt < 2; ++kt) {
        const int slot = (kt * 4 + quad) ^ (r & 7);
        bfr[nt][kt] = *reinterpret_cast<const bf16x8_t*>(&Bs[r * 64 + slot * 8]);
      }
    }
#pragma unroll
    for (int mt = 0; mt < 4; ++mt)
#pragma unroll
      for (int nt = 0; nt < 2; ++nt) {
        acc[mt][nt] = __builtin_amdgcn_mfma_f32_16x16x32_bf16(
            af[mt][0], bfr[nt][0], acc[mt][nt], 0, 0, 0);
        acc[mt][nt] = __builtin_amdgcn_mfma_f32_16x16x32_bf16(
            af[mt][1], bfr[nt][1], acc[mt][nt], 0, 0, 0);
      }
  }

#pragma unroll
  for (int mt = 0; mt < 4; ++mt)
#pragma unroll
    for (int i = 0; i < 4; ++i) {
      const size_t rowg = (size_t)(bm + wm + mt * 16 + quad * 4 + i);
#pragma unroll
      for (int nt = 0; nt < 2; ++nt) {
        const int colg = bn + wn + nt * 16 + l15;
        out[rowg * N + colg] = acc[mt][nt][i] + bias[colg];
      }
    }
}

// ---------------------------------------------------------------------------
// ksum[t][d] = sum_i K[t][i*64+d].  One wave per token, 4 tokens/block.
// ---------------------------------------------------------------------------
__global__ __launch_bounds__(256) void ksum_kernel(
    const unsigned short* __restrict__ Kb, float* __restrict__ ks)
{
  const int t = blockIdx.x * 4 + (threadIdx.x >> 6);
  const int j = threadIdx.x & 63;
  const uint4* row = reinterpret_cast<const uint4*>(Kb + (size_t)t * INNER);
  float s[8] = {0.f, 0.f, 0.f, 0.f, 0.f, 0.f, 0.f, 0.f};
#pragma unroll
  for (int m = 0; m < 8; ++m) {
    const uint4 u = row[j + 64 * m];
    s[0] += __uint_as_float((u.x & 0xFFFFu) << 16);
    s[1] += __uint_as_float(u.x & 0xFFFF0000u);
    s[2] += __uint_as_float((u.y & 0xFFFFu) << 16);
    s[3] += __uint_as_float(u.y & 0xFFFF0000u);
    s[4] += __uint_as_float((u.z & 0xFFFFu) << 16);
    s[5] += __uint_as_float(u.z & 0xFFFF0000u);
    s[6] += __uint_as_float((u.w & 0xFFFFu) << 16);
    s[7] += __uint_as_float(u.w & 0xFFFF0000u);
  }
#pragma unroll
  for (int off = 8; off < 64; off <<= 1)
#pragma unroll
    for (int e = 0; e < 8; ++e) s[e] += __shfl_xor(s[e], off, 64);
  if (j < 8) {
    float4* dst = reinterpret_cast<float4*>(ks + t * 64 + j * 8);
    float4 lo, hi;
    lo.x = s[0]; lo.y = s[1]; lo.z = s[2]; lo.w = s[3];
    hi.x = s[4]; hi.y = s[5]; hi.z = s[6]; hi.w = s[7];
    dst[0] = lo; dst[1] = hi;
  }
}

// ---------------------------------------------------------------------------
// MFMA attention: one wave per token, 4 tokens/block, zero LDS.
// ---------------------------------------------------------------------------
__global__ __launch_bounds__(256) void attn_mfma(
    const unsigned short* __restrict__ Qb, const unsigned short* __restrict__ Vb,
    const float* __restrict__ ksum, unsigned short* __restrict__ Ab)
{
  const int t    = blockIdx.x * 4 + (threadIdx.x >> 6);
  const int lane = threadIdx.x & 63;
  const int l15  = lane & 15;
  const int quad = lane >> 4;
  const size_t base = (size_t)t * INNER;

  union VU { bf16x8_t v; unsigned short u[8]; };

  float ksv[2][8];
#pragma unroll
  for (int kt = 0; kt < 2; ++kt) {
    const float4* p = reinterpret_cast<const float4*>(ksum + t * 64 + kt * 32 + quad * 8);
    const float4 a = p[0], b = p[1];
    ksv[kt][0] = a.x; ksv[kt][1] = a.y; ksv[kt][2] = a.z; ksv[kt][3] = a.w;
    ksv[kt][4] = b.x; ksv[kt][5] = b.y; ksv[kt][6] = b.z; ksv[kt][7] = b.w;
  }

  bf16x8_t vs[4][2];
#pragma unroll
  for (int nt = 0; nt < 4; ++nt)
#pragma unroll
    for (int kt = 0; kt < 2; ++kt) {
      VU vr, vo;
      vr.v = *reinterpret_cast<const bf16x8_t*>(
          Vb + base + (size_t)(nt * 16 + l15) * 64 + kt * 32 + quad * 8);
#pragma unroll
      for (int j = 0; j < 8; ++j)
        vo.u[j] = f2bfbits(bfbits2f(vr.u[j]) * ksv[kt][j]);
      vs[nt][kt] = vo.v;
    }

  bf16x8_t qf[4][2];
  float qn[4] = {0.f, 0.f, 0.f, 0.f};
#pragma unroll
  for (int mt = 0; mt < 4; ++mt)
#pragma unroll
    for (int kt = 0; kt < 2; ++kt) {
      VU qr;
      qr.v = *reinterpret_cast<const bf16x8_t*>(
          Qb + base + (size_t)(mt * 16 + l15) * 64 + kt * 32 + quad * 8);
      qf[mt][kt] = qr.v;
#pragma unroll
      for (int j = 0; j < 8; ++j)
        qn[mt] += bfbits2f(qr.u[j]) * ksv[kt][j];
    }
#pragma unroll
  for (int mt = 0; mt < 4; ++mt) {
    qn[mt] += __shfl_xor(qn[mt], 16, 64);
    qn[mt] += __shfl_xor(qn[mt], 32, 64);
  }

  f32x4_t acc[4][4];
#pragma unroll
  for (int mt = 0; mt < 4; ++mt)
#pragma unroll
    for (int nt = 0; nt < 4; ++nt) acc[mt][nt] = (f32x4_t){0.f, 0.f, 0.f, 0.f};

#pragma unroll
  for (int mt = 0; mt < 4; ++mt)
#pragma unroll
    for (int nt = 0; nt < 4; ++nt) {
      acc[mt][nt] = __builtin_amdgcn_mfma_f32_16x16x32_bf16(
          qf[mt][0], vs[nt][0], acc[mt][nt], 0, 0, 0);
      acc[mt][nt] = __builtin_amdgcn_mfma_f32_16x16x32_bf16(
          qf[mt][1], vs[nt][1], acc[mt][nt], 0, 0, 0);
    }

#pragma unroll
  for (int mt = 0; mt < 4; ++mt)
#pragma unroll
    for (int i = 0; i < 4; ++i) {
      const float inv = 1.f / (__shfl(qn[mt], quad * 4 + i, 64) + EPS);
      const size_t roff = base + (size_t)(mt * 16 + quad * 4 + i) * 64;
#pragma unroll
      for (int nt = 0; nt < 4; ++nt)
        Ab[roff + nt * 16 + l15] = f2bfbits(acc[mt][nt][i] * inv);
    }
}

// ---------------------------------------------------------------------------
// Buffers (ws = 130 MB):
//  ws   @0      : K (transient) -> Q -> A (in place)
//  ws   @64MB   : V ; first 8MB reused for Wo^T after attn
//  ws   @128MB  : ksum (fp32 8192x64, 2MB)
//  d_out@0      : Xb (bf16 8192x1024, 16MB)       — dead before gemm_out writes
//  d_out@16MB   : WtKV (bf16 8192x1024, 16MB)     — then WqT (8MB)
// ---------------------------------------------------------------------------
extern "C" void kernel_launch(void* const* d_in, const int* in_sizes, int n_in,
                              void* d_out, int out_size, void* d_ws, size_t ws_size,
                              hipStream_t stream)
{
  const float* x  = (const float*)d_in[0];
  const float* Wq = (const float*)d_in[1];
  const float* Wk = (const float*)d_in[2];
  const float* Wv = (const float*)d_in[3];
  const float* Wo = (const float*)d_in[4];
  const float* bo = (const float*)d_in[5];
  float* out = (float*)d_out;

  uint8_t* ws = (uint8_t*)d_ws;
  const size_t HALF = (size_t)M_TOK * INNER * sizeof(bf16);  // 64 MB
  unsigned short* KQA = (unsigned short*)ws;            // K -> Q -> A
  unsigned short* Vb  = (unsigned short*)(ws + HALF);   // V ; then Wo^T
  float* ks           = (float*)(ws + 2 * HALF);

  unsigned short* Xb   = (unsigned short*)d_out;                           // 16 MB
  unsigned short* WtKV = (unsigned short*)((uint8_t*)d_out + (16u << 20)); // 16 MB
  unsigned short* WqT  = WtKV;   // reused after gemm_kv
  unsigned short* Wot  = Vb;     // Wo^T over dead V (after attn)

  const dim3 blk(256);
  const dim3 blk512(512);

  // fused prep: castx (8192 blocks) + Wk^T (4096) + Wv^T (4096)
  prep_kernel<<<dim3(16384), blk, 0, stream>>>(x, Xb, Wk, Wv, WtKV);

  // fused K+V projection: 256^2 slip-pipelined, DUAL epilogue (relu->K, id->V)
  gemm256<0, 1><<<dim3(2 * INNER / 256, M_TOK / 256), blk512, 0, stream>>>(
      Xb, WtKV, KQA, Vb, 2 * INNER, DIM);

  ksum_kernel<<<dim3(M_TOK / 4), blk, 0, stream>>>(KQA, ks);

  tcast_kernel<<<dim3(INNER / 32, DIM / 32), blk, 0, stream>>>(
      Wq, WqT, DIM, INNER);

  // Q projection: relu * QSCALE, overwrites dead K
  gemm256<2, 0><<<dim3(INNER / 256, M_TOK / 256), blk512, 0, stream>>>(
      Xb, WqT, KQA, nullptr, INNER, DIM);

  attn_mfma<<<dim3(M_TOK / 4), blk, 0, stream>>>(KQA, Vb, ks, KQA);  // A in place

  tcast_kernel<<<dim3(DIM / 32, INNER / 32), blk, 0, stream>>>(
      Wo, Wot, INNER, DIM);  // over dead V

  gemm_out_bf16<<<dim3(DIM / 64, M_TOK / 128), blk, 0, stream>>>(
      KQA, Wot, bo, out, M_TOK, DIM, INNER);
}

// Round 9
// 453.862 us; speedup vs baseline: 1.1104x; 1.0682x over previous
//
#include <hip/hip_runtime.h>
#include <hip/hip_bf16.h>
#include <cstdint>

// Problem constants (b=2, s=4096, dim=1024, heads=64, dim_head=64)
#define M_TOK 8192
#define DIM   1024
#define INNER 4096
#define HEADS 64
#define DH    64
#define QSCALE 0.125f      // 64^-0.5
#define EPS    1e-6f

typedef __hip_bfloat16 bf16;
typedef __bf16 bf16x8_t __attribute__((ext_vector_type(8)));
typedef float f32x4_t __attribute__((ext_vector_type(4)));

__device__ __forceinline__ float bfbits2f(unsigned short u) {
  return __uint_as_float(((unsigned)u) << 16);
}
__device__ __forceinline__ unsigned short f2bfbits(float f) {
  __hip_bfloat16 h = __float2bfloat16(f);
  unsigned short u;
  __builtin_memcpy(&u, &h, 2);
  return u;
}

// async global->LDS, 16B per lane. LDS dst must be wave-uniform base + lane*16.
__device__ __forceinline__ void load_lds16(const void* g, void* l) {
  __builtin_amdgcn_global_load_lds(
      (__attribute__((address_space(1))) void*)g,
      (__attribute__((address_space(3))) void*)l, 16, 0, 0);
}

__device__ __forceinline__ void asm_barrier() {
  asm volatile("s_barrier" ::: "memory");
}

// Counted lgkm wait + sched_barrier(0).  SB required (rule #18): hipcc hoists
// register-only MFMAs above inline-asm lgkmcnt despite the "memory" clobber.
#define LGKM_SB(N) do { \
    asm volatile("s_waitcnt lgkmcnt(" #N ")" ::: "memory"); \
    __builtin_amdgcn_sched_barrier(0); } while (0)

// XCD-aware block swizzle: XCD x owns M-tiles [x*gy/8, (x+1)*gy/8), N-major
// within the XCD.
__device__ __forceinline__ void swizzle_xy(int& bx, int& by) {
  const int gx = gridDim.x, gy = gridDim.y;
  const int id  = blockIdx.x + gx * blockIdx.y;
  const int per = gy >> 3;          // M-tiles per XCD (gy % 8 == 0)
  const int xcd = id & 7;
  const int s   = id >> 3;
  by = xcd * per + (s % per);
  bx = s / per;
}

// ---------------------------------------------------------------------------
// Fused prep kernel: castx + Wk^T + Wv^T in ONE launch.
//   blocks [0, 8192)        : cast x fp32 -> bf16 (one float4/thread)
//   blocks [8192, 12288)    : transpose-cast Wk -> WtKV[0:4096*1024)
//   blocks [12288, 16384)   : transpose-cast Wv -> WtKV[4096*1024:...)
//
// R9: Wk^T rows are PERMUTED to dh-major: K output col c = head*64+dh is
// stored at row c' = dh*64 + head.  Effect: in gemm_kv, each K-block's 256
// cols = 4 dh-slices x all 64 heads, and each wave's 64-wide wn window is
// ONE dh x all heads -> ksum[t][dh] = sum_head relu(K) reduces entirely
// in-wave (4-nt sum + 16-lane shfl), no atomics, no K materialization.
// V layout unchanged.  The GEMM itself is blind to B-row permutation.
// ---------------------------------------------------------------------------
__global__ __launch_bounds__(256) void prep_kernel(
    const float* __restrict__ x, unsigned short* __restrict__ xb,
    const float* __restrict__ Wk, const float* __restrict__ Wv,
    unsigned short* __restrict__ WtKV)
{
  const int bid = blockIdx.x;
  if (bid < 8192) {
    const int i = bid * 256 + threadIdx.x;   // exactly 8192*256 float4s
    const float4 v = reinterpret_cast<const float4*>(x)[i];
    ushort4 o;
    o.x = f2bfbits(v.x); o.y = f2bfbits(v.y);
    o.z = f2bfbits(v.z); o.w = f2bfbits(v.w);
    reinterpret_cast<ushort4*>(xb)[i] = o;
    return;
  }
  // transpose-cast role: W [1024][4096] -> Wt [4096][1024], 32x32 tiles
  __shared__ float tile[32][33];
  const int t    = bid - 8192;
  const int z    = t >> 12;               // 0 = Wk (permuted), 1 = Wv
  const int tt   = t & 4095;
  const float* W = z ? Wv : Wk;
  unsigned short* dst = WtKV + (size_t)z * DIM * INNER;
  const int bx = (tt & 127) * 32;         // C offset (C = 4096 -> 128 tiles)
  const int by = (tt >> 7) * 32;          // R offset (R = 1024 -> 32 tiles)
  const int tx = threadIdx.x & 31;
  const int ty = threadIdx.x >> 5;        // 0..7
#pragma unroll
  for (int k = 0; k < 4; ++k)
    tile[ty + k * 8][tx] = W[(size_t)(by + ty + k * 8) * INNER + bx + tx];
  __syncthreads();
#pragma unroll
  for (int k = 0; k < 4; ++k) {
    const int c  = bx + ty + k * 8;                    // output col in [0,4096)
    const int rp = z ? c : (((c & 63) << 6) | (c >> 6));  // dh-major for Wk
    dst[(size_t)rp * DIM + by + tx] = f2bfbits(tile[tx][ty + k * 8]);
  }
}

// ---------------------------------------------------------------------------
// transpose-cast: W [R][C] fp32 -> Wt [C][R] bf16.  32x32 LDS tiles.
// (kept for Wq^T and Wo^T, whose destinations are not free at prep time)
// ---------------------------------------------------------------------------
__global__ __launch_bounds__(256) void tcast_kernel(
    const float* __restrict__ W, unsigned short* __restrict__ Wt, int R, int C)
{
  __shared__ float tile[32][33];
  const int bx = blockIdx.x * 32;   // C offset
  const int by = blockIdx.y * 32;   // R offset
  const int tx = threadIdx.x & 31;
  const int ty = threadIdx.x >> 5;  // 0..7
#pragma unroll
  for (int k = 0; k < 4; ++k)
    tile[ty + k * 8][tx] = W[(size_t)(by + ty + k * 8) * C + bx + tx];
  __syncthreads();
#pragma unroll
  for (int k = 0; k < 4; ++k)
    Wt[(size_t)(bx + ty + k * 8) * R + by + tx] = f2bfbits(tile[tx][ty + k * 8]);
}

// ---------------------------------------------------------------------------
// 256x256 slip-pipelined GEMM (R5-VERIFIED core — main loop unmodified).
// 512 thr = 8 waves (2M x 4N), BK=64.  LDS 128 KB double-buffered.
// Swizzle: slot = chunk^(row&7) (conflict-free, SQ_LDS_BANK_CONFLICT == 0).
//
// Schedule: ONE barrier per K-tile + counted lgkmcnt so each quadrant's MFMA
// overlaps the next quadrant's ds_read delivery (see R5 notes; validated).
//
// R9 epilogue change (DUAL=1 only): K-blocks (bn<4096) do NOT write K.
// With dh-major Wk^T (see prep), each wave's wn window = one dh x 64 heads:
//   ksum[t][dh] = sum over heads of relu(K[t][head][dh])
//   = sum_nt relu(acc) (4 heads in-thread) + shfl_xor reduce over l15
//     (16 lanes x 4 nt = 64 heads), written by l15==0 lanes.
// Each block owns [256 tokens] x [4 dh] exclusively -> plain stores, no
// atomics, no zero-init.  V-blocks write V as before.
// MODE: 0 identity, 1 relu, 2 relu*QSCALE.
// ---------------------------------------------------------------------------
__device__ __forceinline__ void stage_half(
    const unsigned short* __restrict__ G, unsigned short* L,
    int rowbase, int k0, int K, int h, int tid)
{
#pragma unroll
  for (int j = 0; j < 2; ++j) {
    const int q  = h * 1024 + j * 512 + tid;     // chunk index in 256x64 tile
    const int r  = q >> 3;                       // row 0..255
    const int cg = (tid & 7) ^ (r & 7);          // global k-chunk (inverse swz)
    load_lds16(&G[(size_t)(rowbase + r) * K + k0 + cg * 8], &L[q * 8]);
  }
}

__device__ __forceinline__ void read_af4(
    const unsigned short* __restrict__ Ac, bf16x8_t (&af)[8][2],
    int m0, int wm, int l15, int quad)
{
#pragma unroll
  for (int mt = 0; mt < 4; ++mt) {
    const int r = wm + (m0 + mt) * 16 + l15;
#pragma unroll
    for (int kt = 0; kt < 2; ++kt) {
      const int s = (kt * 4 + quad) ^ (r & 7);
      af[m0 + mt][kt] = *reinterpret_cast<const bf16x8_t*>(&Ac[r * 64 + s * 8]);
    }
  }
}

__device__ __forceinline__ void read_bf2(
    const unsigned short* __restrict__ Bc, bf16x8_t (&bfr)[4][2],
    int n0, int wn, int l15, int quad)
{
#pragma unroll
  for (int nt = 0; nt < 2; ++nt) {
    const int r = wn + (n0 + nt) * 16 + l15;
#pragma unroll
    for (int kt = 0; kt < 2; ++kt) {
      const int s = (kt * 4 + quad) ^ (r & 7);
      bfr[n0 + nt][kt] = *reinterpret_cast<const bf16x8_t*>(&Bc[r * 64 + s * 8]);
    }
  }
}

__device__ __forceinline__ void mfma_quad(
    f32x4_t (&acc)[8][4], const bf16x8_t (&af)[8][2],
    const bf16x8_t (&bfr)[4][2], int m0, int n0)
{
  __builtin_amdgcn_s_setprio(1);
#pragma unroll
  for (int mt = m0; mt < m0 + 4; ++mt)
#pragma unroll
    for (int nt = n0; nt < n0 + 2; ++nt) {
      acc[mt][nt] = __builtin_amdgcn_mfma_f32_16x16x32_bf16(
          af[mt][0], bfr[nt][0], acc[mt][nt], 0, 0, 0);
      acc[mt][nt] = __builtin_amdgcn_mfma_f32_16x16x32_bf16(
          af[mt][1], bfr[nt][1], acc[mt][nt], 0, 0, 0);
    }
  __builtin_amdgcn_s_setprio(0);
}

template <int MODE, int DUAL>
__global__ __launch_bounds__(512, 2) void gemm256(
    const unsigned short* __restrict__ A,   // [M][K] bf16
    const unsigned short* __restrict__ Bt,  // [N][K] bf16 (B transposed)
    unsigned short* __restrict__ C0,
    unsigned short* __restrict__ C1,
    float* __restrict__ ks,                 // ksum out (DUAL only)
    int N, int K)
{
  __shared__ __align__(16) unsigned short As[2][256 * 64];  // 64 KB
  __shared__ __align__(16) unsigned short Bs[2][256 * 64];  // 64 KB

  int bxi, byi;
  swizzle_xy(bxi, byi);
  const int tid  = threadIdx.x;
  const int bm   = byi * 256;
  const int bn   = bxi * 256;
  const int lane = tid & 63;
  const int w    = tid >> 6;
  const int wm   = (w >> 2) * 128;   // wave M offset (0/128)
  const int wn   = (w & 3) * 64;     // wave N offset (0/64/128/192)
  const int quad = lane >> 4;
  const int l15  = lane & 15;

  f32x4_t acc[8][4];
#pragma unroll
  for (int mt = 0; mt < 8; ++mt)
#pragma unroll
    for (int nt = 0; nt < 4; ++nt) acc[mt][nt] = (f32x4_t){0.f, 0.f, 0.f, 0.f};

  const int NT = K >> 6;

  bf16x8_t af[8][2], bfr[4][2];

  // ---- prologue: tile0 A+B, tile1 A staged; tile0 resident; seam reads ----
  stage_half(A,  As[0], bm, 0,  K, 0, tid);
  stage_half(A,  As[0], bm, 0,  K, 1, tid);
  stage_half(Bt, Bs[0], bn, 0,  K, 0, tid);
  stage_half(Bt, Bs[0], bn, 0,  K, 1, tid);
  stage_half(A,  As[1], bm, 64, K, 0, tid);
  stage_half(A,  As[1], bm, 64, K, 1, tid);
  asm volatile("s_waitcnt vmcnt(4)" ::: "memory");  // tile0 resident; tile1.A in flight
  asm_barrier();
  __builtin_amdgcn_sched_barrier(0);
  read_af4(As[0], af, 0, wm, l15, quad);   // seam for T=0: af0-3
  read_bf2(Bs[0], bfr, 0, wn, l15, quad);  //               bfr0-1

  for (int T = 0; T < NT; ++T) {
    const int c = T & 1;
    const unsigned short* Ac = As[c];
    const unsigned short* Bc = Bs[c];
    unsigned short* Bnx = Bs[c ^ 1];   // tile T+1 B lands here
    unsigned short* Anx = As[c];       // tile T+2 A lands here
    const int kB = (T + 1) * 64;
    const int kA = (T + 2) * 64;
    const bool pB = (T + 1 < NT);
    const bool pA = (T + 2 < NT);

    // region 1: issue q1 frags; wait seam; MFMA q0 overlaps af4-7 delivery
    read_af4(Ac, af, 4, wm, l15, quad);                 // 8 ds_reads
    LGKM_SB(8);                                         // seam (12) retired
    mfma_quad(acc, af, bfr, 0, 0);                      // q0: m0-3 x n0-1

    // region 2: issue q2 frags + B-stage; wait af4-7; MFMA q1 overlaps
    read_bf2(Bc, bfr, 2, wn, l15, quad);                // 4 ds_reads
    if (pB) stage_half(Bt, Bnx, bn, kB, K, 0, tid);
    LGKM_SB(4);                                         // af4-7 retired
    mfma_quad(acc, af, bfr, 4, 0);                      // q1: m4-7 x n0-1

    // region 3: stages; wait bfr2-3; MFMA q2
    if (pB) stage_half(Bt, Bnx, bn, kB, K, 1, tid);
    if (pA) stage_half(A, Anx, bm, kA, K, 0, tid);      // all As[c] reads retired
    LGKM_SB(0);                                         // bfr2-3 retired
    mfma_quad(acc, af, bfr, 0, 2);                      // q2: m0-3 x n2-3

    // region 4: last stage; MFMA q3; tile-boundary handoff
    if (pA) stage_half(A, Anx, bm, kA, K, 1, tid);
    mfma_quad(acc, af, bfr, 4, 2);                      // q3: m4-7 x n2-3
    if (T < NT - 2) {
      asm volatile("s_waitcnt vmcnt(4)" ::: "memory");  // T+1 resident; T+2.A in flight
    } else {
      asm volatile("s_waitcnt vmcnt(0)" ::: "memory");  // tail drain
    }
    asm_barrier();
    __builtin_amdgcn_sched_barrier(0);
    if (T + 1 < NT) {                                   // seam reads for T+1
      read_af4(As[c ^ 1], af, 0, wm, l15, quad);        // af0-3 (8)
      read_bf2(Bs[c ^ 1], bfr, 0, wn, l15, quad);       // bfr0-1 (4)
    }
  }

  // ---- epilogue ----
  if (DUAL) {
    if (bn < 4096) {
      // K-block: reduce to ksum only (dh-major layout; no K write).
      const int dh = (bn + wn) >> 6;     // this wave's dh column
#pragma unroll
      for (int mt = 0; mt < 8; ++mt)
#pragma unroll
        for (int i = 0; i < 4; ++i) {
          float s = 0.f;
#pragma unroll
          for (int nt = 0; nt < 4; ++nt) s += fmaxf(acc[mt][nt][i], 0.f);
          s += __shfl_xor(s, 1, 16);
          s += __shfl_xor(s, 2, 16);
          s += __shfl_xor(s, 4, 16);
          s += __shfl_xor(s, 8, 16);
          if (l15 == 0) {
            const size_t rowg = (size_t)(bm + wm + mt * 16 + quad * 4 + i);
            ks[rowg * 64 + dh] = s;
          }
        }
    } else {
      const int bnc = bn & 4095;
#pragma unroll
      for (int mt = 0; mt < 8; ++mt)
#pragma unroll
        for (int i = 0; i < 4; ++i) {
          const size_t rowg = (size_t)(bm + wm + mt * 16 + quad * 4 + i);
#pragma unroll
          for (int nt = 0; nt < 4; ++nt)
            C1[rowg * 4096 + bnc + wn + nt * 16 + l15] = f2bfbits(acc[mt][nt][i]);
        }
    }
  } else {
#pragma unroll
    for (int mt = 0; mt < 8; ++mt)
#pragma unroll
      for (int i = 0; i < 4; ++i) {
        const size_t rowg = (size_t)(bm + wm + mt * 16 + quad * 4 + i);
#pragma unroll
        for (int nt = 0; nt < 4; ++nt) {
          float v = acc[mt][nt][i];
          if (MODE >= 1) v = fmaxf(v, 0.f);
          if (MODE == 2) v *= QSCALE;
          C0[rowg * (size_t)N + bn + wn + nt * 16 + l15] = f2bfbits(v);
        }
      }
  }
}

// ---------------------------------------------------------------------------
// Output MFMA GEMM: out[M,N] = A[M,K] @ Bt[N,K]^T + bias[N], fp32 out.
// 128(M) x 64(N) tile, BK=64 (R5-verified structure).  N=1024 too narrow
// for 256^2 tiles (128 blocks would idle half the chip).
// ---------------------------------------------------------------------------
__global__ __launch_bounds__(256) void gemm_out_bf16(
    const unsigned short* __restrict__ A,   // [M][K] bf16
    const unsigned short* __restrict__ Bt,  // [N][K] bf16
    const float* __restrict__ bias,
    float* __restrict__ out, int M, int N, int K)
{
  __shared__ __align__(16) unsigned short As[128 * 64];  // 16 KB
  __shared__ __align__(16) unsigned short Bs[64 * 64];   //  8 KB

  int bxi, byi;
  swizzle_xy(bxi, byi);
  const int tid  = threadIdx.x;
  const int bm   = byi * 128;
  const int bn   = bxi * 64;
  const int lane = tid & 63;
  const int w    = tid >> 6;
  const int wm   = (w & 1) * 64;
  const int wn   = (w >> 1) * 32;
  const int quad = lane >> 4;
  const int l15  = lane & 15;

  f32x4_t acc[4][2];
#pragma unroll
  for (int mt = 0; mt < 4; ++mt)
#pragma unroll
    for (int nt = 0; nt < 2; ++nt) acc[mt][nt] = (f32x4_t){0.f, 0.f, 0.f, 0.f};

  int qa[4], ra[4], ca[4];
#pragma unroll
  for (int j = 0; j < 4; ++j) {
    qa[j] = tid + 256 * j;
    ra[j] = qa[j] >> 3;
    ca[j] = (qa[j] & 7) ^ (ra[j] & 7);
  }
  int qb[2], rb[2], cb[2];
#pragma unroll
  for (int j = 0; j < 2; ++j) {
    qb[j] = tid + 256 * j;
    rb[j] = qb[j] >> 3;
    cb[j] = (qb[j] & 7) ^ (rb[j] & 7);
  }

  for (int k0 = 0; k0 < K; k0 += 64) {
    __syncthreads();
#pragma unroll
    for (int j = 0; j < 4; ++j)
      load_lds16(&A[(size_t)(bm + ra[j]) * K + k0 + ca[j] * 8], &As[qa[j] * 8]);
#pragma unroll
    for (int j = 0; j < 2; ++j)
      load_lds16(&Bt[(size_t)(bn + rb[j]) * K + k0 + cb[j] * 8], &Bs[qb[j] * 8]);
    __syncthreads();

    bf16x8_t af[4][2], bfr[2][2];
#pragma unroll
    for (int mt = 0; mt < 4; ++mt) {
      const int r = wm + mt * 16 + l15;
#pragma unroll
      for (int kt = 0; kt < 2; ++kt) {
        const int slot = (kt * 4 + quad) ^ (r & 7);
        af[mt][kt] = *reinterpret_cast<const bf16x8_t*>(&As[r * 64 + slot * 8]);
      }
    }
#pragma unroll
    for (int nt = 0; nt < 2; ++nt) {
      const int r = wn + nt * 16 + l15;
#pragma unroll
      for (int kt = 0; kt < 2; ++kt) {
        const int slot = (kt * 4 + quad) ^ (r & 7);
        bfr[nt][kt] = *reinterpret_cast<const bf16x8_t*>(&Bs[r * 64 + slot * 8]);
      }
    }
#pragma unroll
    for (int mt = 0; mt < 4; ++mt)
#pragma unroll
      for (int nt = 0; nt < 2; ++nt) {
        acc[mt][nt] = __builtin_amdgcn_mfma_f32_16x16x32_bf16(
            af[mt][0], bfr[nt][0], acc[mt][nt], 0, 0, 0);
        acc[mt][nt] = __builtin_amdgcn_mfma_f32_16x16x32_bf16(
            af[mt][1], bfr[nt][1], acc[mt][nt], 0, 0, 0);
      }
  }

#pragma unroll
  for (int mt = 0; mt < 4; ++mt)
#pragma unroll
    for (int i = 0; i < 4; ++i) {
      const size_t rowg = (size_t)(bm + wm + mt * 16 + quad * 4 + i);
#pragma unroll
      for (int nt = 0; nt < 2; ++nt) {
        const int colg = bn + wn + nt * 16 + l15;
        out[rowg * N + colg] = acc[mt][nt][i] + bias[colg];
      }
    }
}

// ---------------------------------------------------------------------------
// MFMA attention: one wave per token, 4 tokens/block, zero LDS.
// ---------------------------------------------------------------------------
__global__ __launch_bounds__(256) void attn_mfma(
    const unsigned short* __restrict__ Qb, const unsigned short* __restrict__ Vb,
    const float* __restrict__ ksum, unsigned short* __restrict__ Ab)
{
  const int t    = blockIdx.x * 4 + (threadIdx.x >> 6);
  const int lane = threadIdx.x & 63;
  const int l15  = lane & 15;
  const int quad = lane >> 4;
  const size_t base = (size_t)t * INNER;

  union VU { bf16x8_t v; unsigned short u[8]; };

  float ksv[2][8];
#pragma unroll
  for (int kt = 0; kt < 2; ++kt) {
    const float4* p = reinterpret_cast<const float4*>(ksum + t * 64 + kt * 32 + quad * 8);
    const float4 a = p[0], b = p[1];
    ksv[kt][0] = a.x; ksv[kt][1] = a.y; ksv[kt][2] = a.z; ksv[kt][3] = a.w;
    ksv[kt][4] = b.x; ksv[kt][5] = b.y; ksv[kt][6] = b.z; ksv[kt][7] = b.w;
  }

  bf16x8_t vs[4][2];
#pragma unroll
  for (int nt = 0; nt < 4; ++nt)
#pragma unroll
    for (int kt = 0; kt < 2; ++kt) {
      VU vr, vo;
      vr.v = *reinterpret_cast<const bf16x8_t*>(
          Vb + base + (size_t)(nt * 16 + l15) * 64 + kt * 32 + quad * 8);
#pragma unroll
      for (int j = 0; j < 8; ++j)
        vo.u[j] = f2bfbits(bfbits2f(vr.u[j]) * ksv[kt][j]);
      vs[nt][kt] = vo.v;
    }

  bf16x8_t qf[4][2];
  float qn[4] = {0.f, 0.f, 0.f, 0.f};
#pragma unroll
  for (int mt = 0; mt < 4; ++mt)
#pragma unroll
    for (int kt = 0; kt < 2; ++kt) {
      VU qr;
      qr.v = *reinterpret_cast<const bf16x8_t*>(
          Qb + base + (size_t)(mt * 16 + l15) * 64 + kt * 32 + quad * 8);
      qf[mt][kt] = qr.v;
#pragma unroll
      for (int j = 0; j < 8; ++j)
        qn[mt] += bfbits2f(qr.u[j]) * ksv[kt][j];
    }
#pragma unroll
  for (int mt = 0; mt < 4; ++mt) {
    qn[mt] += __shfl_xor(qn[mt], 16, 64);
    qn[mt] += __shfl_xor(qn[mt], 32, 64);
  }

  f32x4_t acc[4][4];
#pragma unroll
  for (int mt = 0; mt < 4; ++mt)
#pragma unroll
    for (int nt = 0; nt < 4; ++nt) acc[mt][nt] = (f32x4_t){0.f, 0.f, 0.f, 0.f};

#pragma unroll
  for (int mt = 0; mt < 4; ++mt)
#pragma unroll
    for (int nt = 0; nt < 4; ++nt) {
      acc[mt][nt] = __builtin_amdgcn_mfma_f32_16x16x32_bf16(
          qf[mt][0], vs[nt][0], acc[mt][nt], 0, 0, 0);
      acc[mt][nt] = __builtin_amdgcn_mfma_f32_16x16x32_bf16(
          qf[mt][1], vs[nt][1], acc[mt][nt], 0, 0, 0);
    }

#pragma unroll
  for (int mt = 0; mt < 4; ++mt)
#pragma unroll
    for (int i = 0; i < 4; ++i) {
      const float inv = 1.f / (__shfl(qn[mt], quad * 4 + i, 64) + EPS);
      const size_t roff = base + (size_t)(mt * 16 + quad * 4 + i) * 64;
#pragma unroll
      for (int nt = 0; nt < 4; ++nt)
        Ab[roff + nt * 16 + l15] = f2bfbits(acc[mt][nt][i] * inv);
    }
}

// ---------------------------------------------------------------------------
// Buffers (ws = 130 MB):
//  ws   @0      : Q -> A (in place)  [K is never materialized — R9]
//  ws   @64MB   : V ; first 8MB reused for Wo^T after attn
//  ws   @128MB  : ksum (fp32 8192x64, 2MB) — written by gemm_kv epilogue
//  d_out@0      : Xb (bf16 8192x1024, 16MB)       — dead before gemm_out writes
//  d_out@16MB   : WtKV (bf16 8192x1024, 16MB)     — then WqT (8MB)
// ---------------------------------------------------------------------------
extern "C" void kernel_launch(void* const* d_in, const int* in_sizes, int n_in,
                              void* d_out, int out_size, void* d_ws, size_t ws_size,
                              hipStream_t stream)
{
  const float* x  = (const float*)d_in[0];
  const float* Wq = (const float*)d_in[1];
  const float* Wk = (const float*)d_in[2];
  const float* Wv = (const float*)d_in[3];
  const float* Wo = (const float*)d_in[4];
  const float* bo = (const float*)d_in[5];
  float* out = (float*)d_out;

  uint8_t* ws = (uint8_t*)d_ws;
  const size_t HALF = (size_t)M_TOK * INNER * sizeof(bf16);  // 64 MB
  unsigned short* KQA = (unsigned short*)ws;            // Q -> A
  unsigned short* Vb  = (unsigned short*)(ws + HALF);   // V ; then Wo^T
  float* ks           = (float*)(ws + 2 * HALF);

  unsigned short* Xb   = (unsigned short*)d_out;                           // 16 MB
  unsigned short* WtKV = (unsigned short*)((uint8_t*)d_out + (16u << 20)); // 16 MB
  unsigned short* WqT  = WtKV;   // reused after gemm_kv
  unsigned short* Wot  = Vb;     // Wo^T over dead V (after attn)

  const dim3 blk(256);
  const dim3 blk512(512);

  // fused prep: castx (8192 blocks) + Wk^T dh-major (4096) + Wv^T (4096)
  prep_kernel<<<dim3(16384), blk, 0, stream>>>(x, Xb, Wk, Wv, WtKV);

  // fused K+V projection: K-blocks reduce straight to ksum (no K write),
  // V-blocks write V.  256^2 slip-pipelined (R5-verified core).
  gemm256<0, 1><<<dim3(2 * INNER / 256, M_TOK / 256), blk512, 0, stream>>>(
      Xb, WtKV, nullptr, Vb, ks, 2 * INNER, DIM);

  tcast_kernel<<<dim3(INNER / 32, DIM / 32), blk, 0, stream>>>(
      Wq, WqT, DIM, INNER);

  // Q projection: relu * QSCALE -> KQA
  gemm256<2, 0><<<dim3(INNER / 256, M_TOK / 256), blk512, 0, stream>>>(
      Xb, WqT, KQA, nullptr, nullptr, INNER, DIM);

  attn_mfma<<<dim3(M_TOK / 4), blk, 0, stream>>>(KQA, Vb, ks, KQA);  // A in place

  tcast_kernel<<<dim3(DIM / 32, INNER / 32), blk, 0, stream>>>(
      Wo, Wot, INNER, DIM);  // over dead V

  gemm_out_bf16<<<dim3(DIM / 64, M_TOK / 128), blk, 0, stream>>>(
      KQA, Wot, bo, out, M_TOK, DIM, INNER);
}

// Round 10
// 436.465 us; speedup vs baseline: 1.1546x; 1.0399x over previous
//
#include <hip/hip_runtime.h>
#include <hip/hip_bf16.h>
#include <cstdint>

// Problem constants (b=2, s=4096, dim=1024, heads=64, dim_head=64)
#define M_TOK 8192
#define DIM   1024
#define INNER 4096
#define HEADS 64
#define DH    64
#define QSCALE 0.125f      // 64^-0.5
#define EPS    1e-6f

typedef __hip_bfloat16 bf16;
typedef __bf16 bf16x8_t __attribute__((ext_vector_type(8)));
typedef float f32x4_t __attribute__((ext_vector_type(4)));

__device__ __forceinline__ float bfbits2f(unsigned short u) {
  return __uint_as_float(((unsigned)u) << 16);
}
__device__ __forceinline__ unsigned short f2bfbits(float f) {
  __hip_bfloat16 h = __float2bfloat16(f);
  unsigned short u;
  __builtin_memcpy(&u, &h, 2);
  return u;
}

// async global->LDS, 16B per lane. LDS dst must be wave-uniform base + lane*16.
__device__ __forceinline__ void load_lds16(const void* g, void* l) {
  __builtin_amdgcn_global_load_lds(
      (__attribute__((address_space(1))) void*)g,
      (__attribute__((address_space(3))) void*)l, 16, 0, 0);
}

__device__ __forceinline__ void asm_barrier() {
  asm volatile("s_barrier" ::: "memory");
}

// Counted lgkm wait + sched_barrier(0).  SB required (rule #18): hipcc hoists
// register-only MFMAs above inline-asm lgkmcnt despite the "memory" clobber.
#define LGKM_SB(N) do { \
    asm volatile("s_waitcnt lgkmcnt(" #N ")" ::: "memory"); \
    __builtin_amdgcn_sched_barrier(0); } while (0)

// XCD-aware block swizzle: XCD x owns M-tiles [x*gy/8, (x+1)*gy/8), N-major
// within the XCD.
__device__ __forceinline__ void swizzle_xy(int& bx, int& by) {
  const int gx = gridDim.x, gy = gridDim.y;
  const int id  = blockIdx.x + gx * blockIdx.y;
  const int per = gy >> 3;          // M-tiles per XCD (gy % 8 == 0)
  const int xcd = id & 7;
  const int s   = id >> 3;
  by = xcd * per + (s % per);
  bx = s / per;
}

// ---------------------------------------------------------------------------
// Fused prep kernel: castx + Wk^T + Wv^T in ONE launch.
//   blocks [0, 8192)        : cast x fp32 -> bf16 (one float4/thread)
//   blocks [8192, 12288)    : transpose-cast Wk -> WtKV[0:4096*1024) (dh-major)
//   blocks [12288, 16384)   : transpose-cast Wv -> WtKV[4096*1024:...)
//
// Wk^T rows are PERMUTED to dh-major: K output col c = head*64+dh is stored
// at row c' = dh*64 + head -> in gemm_kv each wave's 64-wide wn window is
// ONE dh x all 64 heads -> ksum reduces in-wave, K never materialized (R9).
// ---------------------------------------------------------------------------
__global__ __launch_bounds__(256) void prep_kernel(
    const float* __restrict__ x, unsigned short* __restrict__ xb,
    const float* __restrict__ Wk, const float* __restrict__ Wv,
    unsigned short* __restrict__ WtKV)
{
  const int bid = blockIdx.x;
  if (bid < 8192) {
    const int i = bid * 256 + threadIdx.x;   // exactly 8192*256 float4s
    const float4 v = reinterpret_cast<const float4*>(x)[i];
    ushort4 o;
    o.x = f2bfbits(v.x); o.y = f2bfbits(v.y);
    o.z = f2bfbits(v.z); o.w = f2bfbits(v.w);
    reinterpret_cast<ushort4*>(xb)[i] = o;
    return;
  }
  // transpose-cast role: W [1024][4096] -> Wt [4096][1024], 32x32 tiles
  __shared__ float tile[32][33];
  const int t    = bid - 8192;
  const int z    = t >> 12;               // 0 = Wk (permuted), 1 = Wv
  const int tt   = t & 4095;
  const float* W = z ? Wv : Wk;
  unsigned short* dst = WtKV + (size_t)z * DIM * INNER;
  const int bx = (tt & 127) * 32;         // C offset (C = 4096 -> 128 tiles)
  const int by = (tt >> 7) * 32;          // R offset (R = 1024 -> 32 tiles)
  const int tx = threadIdx.x & 31;
  const int ty = threadIdx.x >> 5;        // 0..7
#pragma unroll
  for (int k = 0; k < 4; ++k)
    tile[ty + k * 8][tx] = W[(size_t)(by + ty + k * 8) * INNER + bx + tx];
  __syncthreads();
#pragma unroll
  for (int k = 0; k < 4; ++k) {
    const int c  = bx + ty + k * 8;                    // output col in [0,4096)
    const int rp = z ? c : (((c & 63) << 6) | (c >> 6));  // dh-major for Wk
    dst[(size_t)rp * DIM + by + tx] = f2bfbits(tile[tx][ty + k * 8]);
  }
}

// ---------------------------------------------------------------------------
// transpose-cast: W [R][C] fp32 -> Wt [C][R] bf16.  32x32 LDS tiles.
// (kept for Wq^T and Wo^T, whose destinations are not free at prep time)
// ---------------------------------------------------------------------------
__global__ __launch_bounds__(256) void tcast_kernel(
    const float* __restrict__ W, unsigned short* __restrict__ Wt, int R, int C)
{
  __shared__ float tile[32][33];
  const int bx = blockIdx.x * 32;   // C offset
  const int by = blockIdx.y * 32;   // R offset
  const int tx = threadIdx.x & 31;
  const int ty = threadIdx.x >> 5;  // 0..7
#pragma unroll
  for (int k = 0; k < 4; ++k)
    tile[ty + k * 8][tx] = W[(size_t)(by + ty + k * 8) * C + bx + tx];
  __syncthreads();
#pragma unroll
  for (int k = 0; k < 4; ++k)
    Wt[(size_t)(bx + ty + k * 8) * R + by + tx] = f2bfbits(tile[tx][ty + k * 8]);
}

// ---------------------------------------------------------------------------
// 256x256 slip-pipelined GEMM (R5-VERIFIED core — main loop unmodified).
// 512 thr = 8 waves (2M x 4N), BK=64.  LDS 128 KB double-buffered.
// Swizzle: slot = chunk^(row&7) (conflict-free, SQ_LDS_BANK_CONFLICT == 0).
//
// DUAL=1 epilogue: K-blocks (bn<4096) reduce relu(K) straight to ksum
// (dh-major Wk^T; no K write; R9-verified).  V-blocks write V.
// MODE: 0 identity, 1 relu, 2 relu*QSCALE.
// ---------------------------------------------------------------------------
__device__ __forceinline__ void stage_half(
    const unsigned short* __restrict__ G, unsigned short* L,
    int rowbase, int k0, int K, int h, int tid)
{
#pragma unroll
  for (int j = 0; j < 2; ++j) {
    const int q  = h * 1024 + j * 512 + tid;     // chunk index in 256x64 tile
    const int r  = q >> 3;                       // row 0..255
    const int cg = (tid & 7) ^ (r & 7);          // global k-chunk (inverse swz)
    load_lds16(&G[(size_t)(rowbase + r) * K + k0 + cg * 8], &L[q * 8]);
  }
}

__device__ __forceinline__ void read_af4(
    const unsigned short* __restrict__ Ac, bf16x8_t (&af)[8][2],
    int m0, int wm, int l15, int quad)
{
#pragma unroll
  for (int mt = 0; mt < 4; ++mt) {
    const int r = wm + (m0 + mt) * 16 + l15;
#pragma unroll
    for (int kt = 0; kt < 2; ++kt) {
      const int s = (kt * 4 + quad) ^ (r & 7);
      af[m0 + mt][kt] = *reinterpret_cast<const bf16x8_t*>(&Ac[r * 64 + s * 8]);
    }
  }
}

__device__ __forceinline__ void read_bf2(
    const unsigned short* __restrict__ Bc, bf16x8_t (&bfr)[4][2],
    int n0, int wn, int l15, int quad)
{
#pragma unroll
  for (int nt = 0; nt < 2; ++nt) {
    const int r = wn + (n0 + nt) * 16 + l15;
#pragma unroll
    for (int kt = 0; kt < 2; ++kt) {
      const int s = (kt * 4 + quad) ^ (r & 7);
      bfr[n0 + nt][kt] = *reinterpret_cast<const bf16x8_t*>(&Bc[r * 64 + s * 8]);
    }
  }
}

__device__ __forceinline__ void mfma_quad(
    f32x4_t (&acc)[8][4], const bf16x8_t (&af)[8][2],
    const bf16x8_t (&bfr)[4][2], int m0, int n0)
{
  __builtin_amdgcn_s_setprio(1);
#pragma unroll
  for (int mt = m0; mt < m0 + 4; ++mt)
#pragma unroll
    for (int nt = n0; nt < n0 + 2; ++nt) {
      acc[mt][nt] = __builtin_amdgcn_mfma_f32_16x16x32_bf16(
          af[mt][0], bfr[nt][0], acc[mt][nt], 0, 0, 0);
      acc[mt][nt] = __builtin_amdgcn_mfma_f32_16x16x32_bf16(
          af[mt][1], bfr[nt][1], acc[mt][nt], 0, 0, 0);
    }
  __builtin_amdgcn_s_setprio(0);
}

template <int MODE, int DUAL>
__global__ __launch_bounds__(512, 2) void gemm256(
    const unsigned short* __restrict__ A,   // [M][K] bf16
    const unsigned short* __restrict__ Bt,  // [N][K] bf16 (B transposed)
    unsigned short* __restrict__ C0,
    unsigned short* __restrict__ C1,
    float* __restrict__ ks,                 // ksum out (DUAL only)
    int N, int K)
{
  __shared__ __align__(16) unsigned short As[2][256 * 64];  // 64 KB
  __shared__ __align__(16) unsigned short Bs[2][256 * 64];  // 64 KB

  int bxi, byi;
  swizzle_xy(bxi, byi);
  const int tid  = threadIdx.x;
  const int bm   = byi * 256;
  const int bn   = bxi * 256;
  const int lane = tid & 63;
  const int w    = tid >> 6;
  const int wm   = (w >> 2) * 128;   // wave M offset (0/128)
  const int wn   = (w & 3) * 64;     // wave N offset (0/64/128/192)
  const int quad = lane >> 4;
  const int l15  = lane & 15;

  f32x4_t acc[8][4];
#pragma unroll
  for (int mt = 0; mt < 8; ++mt)
#pragma unroll
    for (int nt = 0; nt < 4; ++nt) acc[mt][nt] = (f32x4_t){0.f, 0.f, 0.f, 0.f};

  const int NT = K >> 6;

  bf16x8_t af[8][2], bfr[4][2];

  // ---- prologue: tile0 A+B, tile1 A staged; tile0 resident; seam reads ----
  stage_half(A,  As[0], bm, 0,  K, 0, tid);
  stage_half(A,  As[0], bm, 0,  K, 1, tid);
  stage_half(Bt, Bs[0], bn, 0,  K, 0, tid);
  stage_half(Bt, Bs[0], bn, 0,  K, 1, tid);
  stage_half(A,  As[1], bm, 64, K, 0, tid);
  stage_half(A,  As[1], bm, 64, K, 1, tid);
  asm volatile("s_waitcnt vmcnt(4)" ::: "memory");  // tile0 resident; tile1.A in flight
  asm_barrier();
  __builtin_amdgcn_sched_barrier(0);
  read_af4(As[0], af, 0, wm, l15, quad);   // seam for T=0: af0-3
  read_bf2(Bs[0], bfr, 0, wn, l15, quad);  //               bfr0-1

  for (int T = 0; T < NT; ++T) {
    const int c = T & 1;
    const unsigned short* Ac = As[c];
    const unsigned short* Bc = Bs[c];
    unsigned short* Bnx = Bs[c ^ 1];   // tile T+1 B lands here
    unsigned short* Anx = As[c];       // tile T+2 A lands here
    const int kB = (T + 1) * 64;
    const int kA = (T + 2) * 64;
    const bool pB = (T + 1 < NT);
    const bool pA = (T + 2 < NT);

    // region 1: issue q1 frags; wait seam; MFMA q0 overlaps af4-7 delivery
    read_af4(Ac, af, 4, wm, l15, quad);                 // 8 ds_reads
    LGKM_SB(8);                                         // seam (12) retired
    mfma_quad(acc, af, bfr, 0, 0);                      // q0: m0-3 x n0-1

    // region 2: issue q2 frags + B-stage; wait af4-7; MFMA q1 overlaps
    read_bf2(Bc, bfr, 2, wn, l15, quad);                // 4 ds_reads
    if (pB) stage_half(Bt, Bnx, bn, kB, K, 0, tid);
    LGKM_SB(4);                                         // af4-7 retired
    mfma_quad(acc, af, bfr, 4, 0);                      // q1: m4-7 x n0-1

    // region 3: stages; wait bfr2-3; MFMA q2
    if (pB) stage_half(Bt, Bnx, bn, kB, K, 1, tid);
    if (pA) stage_half(A, Anx, bm, kA, K, 0, tid);      // all As[c] reads retired
    LGKM_SB(0);                                         // bfr2-3 retired
    mfma_quad(acc, af, bfr, 0, 2);                      // q2: m0-3 x n2-3

    // region 4: last stage; MFMA q3; tile-boundary handoff
    if (pA) stage_half(A, Anx, bm, kA, K, 1, tid);
    mfma_quad(acc, af, bfr, 4, 2);                      // q3: m4-7 x n2-3
    if (T < NT - 2) {
      asm volatile("s_waitcnt vmcnt(4)" ::: "memory");  // T+1 resident; T+2.A in flight
    } else {
      asm volatile("s_waitcnt vmcnt(0)" ::: "memory");  // tail drain
    }
    asm_barrier();
    __builtin_amdgcn_sched_barrier(0);
    if (T + 1 < NT) {                                   // seam reads for T+1
      read_af4(As[c ^ 1], af, 0, wm, l15, quad);        // af0-3 (8)
      read_bf2(Bs[c ^ 1], bfr, 0, wn, l15, quad);       // bfr0-1 (4)
    }
  }

  // ---- epilogue ----
  if (DUAL) {
    if (bn < 4096) {
      // K-block: reduce to ksum only (dh-major layout; no K write).
      const int dh = (bn + wn) >> 6;     // this wave's dh column
#pragma unroll
      for (int mt = 0; mt < 8; ++mt)
#pragma unroll
        for (int i = 0; i < 4; ++i) {
          float s = 0.f;
#pragma unroll
          for (int nt = 0; nt < 4; ++nt) s += fmaxf(acc[mt][nt][i], 0.f);
          s += __shfl_xor(s, 1, 16);
          s += __shfl_xor(s, 2, 16);
          s += __shfl_xor(s, 4, 16);
          s += __shfl_xor(s, 8, 16);
          if (l15 == 0) {
            const size_t rowg = (size_t)(bm + wm + mt * 16 + quad * 4 + i);
            ks[rowg * 64 + dh] = s;
          }
        }
    } else {
      const int bnc = bn & 4095;
#pragma unroll
      for (int mt = 0; mt < 8; ++mt)
#pragma unroll
        for (int i = 0; i < 4; ++i) {
          const size_t rowg = (size_t)(bm + wm + mt * 16 + quad * 4 + i);
#pragma unroll
          for (int nt = 0; nt < 4; ++nt)
            C1[rowg * 4096 + bnc + wn + nt * 16 + l15] = f2bfbits(acc[mt][nt][i]);
        }
    }
  } else {
#pragma unroll
    for (int mt = 0; mt < 8; ++mt)
#pragma unroll
      for (int i = 0; i < 4; ++i) {
        const size_t rowg = (size_t)(bm + wm + mt * 16 + quad * 4 + i);
#pragma unroll
        for (int nt = 0; nt < 4; ++nt) {
          float v = acc[mt][nt][i];
          if (MODE >= 1) v = fmaxf(v, 0.f);
          if (MODE == 2) v *= QSCALE;
          C0[rowg * (size_t)N + bn + wn + nt * 16 + l15] = f2bfbits(v);
        }
      }
  }
}

// ---------------------------------------------------------------------------
// Output MFMA GEMM (R10): out[M,N] = A[M,K] @ Bt[N,K]^T + bias[N], fp32 out.
// 128x128 tile, BK=64 — the R0-verified drain-style 128^2 structure
// (m97 class, 861-912 TF), replacing the 128x64 tile (~600 TF, was the
// longest remaining kernel at ~110 µs for only 68.7 GFLOP).
// 4 waves (2x2 of 64x64), LDS 32 KB single-buffered, __syncthreads-drained
// global_load_lds staging, proven chunk^row swizzle.
// Grid: (N/128 = 8, M/128 = 64) = 512 blocks = 2/CU.
// ---------------------------------------------------------------------------
__global__ __launch_bounds__(256) void gemm_out128(
    const unsigned short* __restrict__ A,   // [M][K] bf16
    const unsigned short* __restrict__ Bt,  // [N][K] bf16
    const float* __restrict__ bias,
    float* __restrict__ out, int N, int K)
{
  __shared__ __align__(16) unsigned short As[128 * 64];  // 16 KB
  __shared__ __align__(16) unsigned short Bs[128 * 64];  // 16 KB

  int bxi, byi;
  swizzle_xy(bxi, byi);
  const int tid  = threadIdx.x;
  const int bm   = byi * 128;
  const int bn   = bxi * 128;
  const int lane = tid & 63;
  const int w    = tid >> 6;
  const int wm   = (w & 1) * 64;
  const int wn   = (w >> 1) * 64;
  const int quad = lane >> 4;
  const int l15  = lane & 15;

  f32x4_t acc[4][4];
#pragma unroll
  for (int mt = 0; mt < 4; ++mt)
#pragma unroll
    for (int nt = 0; nt < 4; ++nt) acc[mt][nt] = (f32x4_t){0.f, 0.f, 0.f, 0.f};

  // 1024 chunks per array, 4/thread. row = q>>3, slot = q&7, c = slot^(row&7)
  int qa[4], ra[4], ca[4];
#pragma unroll
  for (int j = 0; j < 4; ++j) {
    qa[j] = tid + 256 * j;
    ra[j] = qa[j] >> 3;
    ca[j] = (qa[j] & 7) ^ (ra[j] & 7);
  }

  for (int k0 = 0; k0 < K; k0 += 64) {
    __syncthreads();
#pragma unroll
    for (int j = 0; j < 4; ++j) {
      load_lds16(&A [(size_t)(bm + ra[j]) * K + k0 + ca[j] * 8], &As[qa[j] * 8]);
      load_lds16(&Bt[(size_t)(bn + ra[j]) * K + k0 + ca[j] * 8], &Bs[qa[j] * 8]);
    }
    __syncthreads();

    bf16x8_t af[4][2], bfr[4][2];
#pragma unroll
    for (int mt = 0; mt < 4; ++mt) {
      const int r = wm + mt * 16 + l15;
#pragma unroll
      for (int kt = 0; kt < 2; ++kt) {
        const int slot = (kt * 4 + quad) ^ (r & 7);
        af[mt][kt] = *reinterpret_cast<const bf16x8_t*>(&As[r * 64 + slot * 8]);
      }
    }
#pragma unroll
    for (int nt = 0; nt < 4; ++nt) {
      const int r = wn + nt * 16 + l15;
#pragma unroll
      for (int kt = 0; kt < 2; ++kt) {
        const int slot = (kt * 4 + quad) ^ (r & 7);
        bfr[nt][kt] = *reinterpret_cast<const bf16x8_t*>(&Bs[r * 64 + slot * 8]);
      }
    }
#pragma unroll
    for (int mt = 0; mt < 4; ++mt)
#pragma unroll
      for (int nt = 0; nt < 4; ++nt) {
        acc[mt][nt] = __builtin_amdgcn_mfma_f32_16x16x32_bf16(
            af[mt][0], bfr[nt][0], acc[mt][nt], 0, 0, 0);
        acc[mt][nt] = __builtin_amdgcn_mfma_f32_16x16x32_bf16(
            af[mt][1], bfr[nt][1], acc[mt][nt], 0, 0, 0);
      }
  }

#pragma unroll
  for (int mt = 0; mt < 4; ++mt)
#pragma unroll
    for (int i = 0; i < 4; ++i) {
      const size_t rowg = (size_t)(bm + wm + mt * 16 + quad * 4 + i);
#pragma unroll
      for (int nt = 0; nt < 4; ++nt) {
        const int colg = bn + wn + nt * 16 + l15;
        out[rowg * N + colg] = acc[mt][nt][i] + bias[colg];
      }
    }
}

// ---------------------------------------------------------------------------
// MFMA attention: one wave per token, 4 tokens/block, zero LDS.
// ---------------------------------------------------------------------------
__global__ __launch_bounds__(256) void attn_mfma(
    const unsigned short* __restrict__ Qb, const unsigned short* __restrict__ Vb,
    const float* __restrict__ ksum, unsigned short* __restrict__ Ab)
{
  const int t    = blockIdx.x * 4 + (threadIdx.x >> 6);
  const int lane = threadIdx.x & 63;
  const int l15  = lane & 15;
  const int quad = lane >> 4;
  const size_t base = (size_t)t * INNER;

  union VU { bf16x8_t v; unsigned short u[8]; };

  float ksv[2][8];
#pragma unroll
  for (int kt = 0; kt < 2; ++kt) {
    const float4* p = reinterpret_cast<const float4*>(ksum + t * 64 + kt * 32 + quad * 8);
    const float4 a = p[0], b = p[1];
    ksv[kt][0] = a.x; ksv[kt][1] = a.y; ksv[kt][2] = a.z; ksv[kt][3] = a.w;
    ksv[kt][4] = b.x; ksv[kt][5] = b.y; ksv[kt][6] = b.z; ksv[kt][7] = b.w;
  }

  bf16x8_t vs[4][2];
#pragma unroll
  for (int nt = 0; nt < 4; ++nt)
#pragma unroll
    for (int kt = 0; kt < 2; ++kt) {
      VU vr, vo;
      vr.v = *reinterpret_cast<const bf16x8_t*>(
          Vb + base + (size_t)(nt * 16 + l15) * 64 + kt * 32 + quad * 8);
#pragma unroll
      for (int j = 0; j < 8; ++j)
        vo.u[j] = f2bfbits(bfbits2f(vr.u[j]) * ksv[kt][j]);
      vs[nt][kt] = vo.v;
    }

  bf16x8_t qf[4][2];
  float qn[4] = {0.f, 0.f, 0.f, 0.f};
#pragma unroll
  for (int mt = 0; mt < 4; ++mt)
#pragma unroll
    for (int kt = 0; kt < 2; ++kt) {
      VU qr;
      qr.v = *reinterpret_cast<const bf16x8_t*>(
          Qb + base + (size_t)(mt * 16 + l15) * 64 + kt * 32 + quad * 8);
      qf[mt][kt] = qr.v;
#pragma unroll
      for (int j = 0; j < 8; ++j)
        qn[mt] += bfbits2f(qr.u[j]) * ksv[kt][j];
    }
#pragma unroll
  for (int mt = 0; mt < 4; ++mt) {
    qn[mt] += __shfl_xor(qn[mt], 16, 64);
    qn[mt] += __shfl_xor(qn[mt], 32, 64);
  }

  f32x4_t acc[4][4];
#pragma unroll
  for (int mt = 0; mt < 4; ++mt)
#pragma unroll
    for (int nt = 0; nt < 4; ++nt) acc[mt][nt] = (f32x4_t){0.f, 0.f, 0.f, 0.f};

#pragma unroll
  for (int mt = 0; mt < 4; ++mt)
#pragma unroll
    for (int nt = 0; nt < 4; ++nt) {
      acc[mt][nt] = __builtin_amdgcn_mfma_f32_16x16x32_bf16(
          qf[mt][0], vs[nt][0], acc[mt][nt], 0, 0, 0);
      acc[mt][nt] = __builtin_amdgcn_mfma_f32_16x16x32_bf16(
          qf[mt][1], vs[nt][1], acc[mt][nt], 0, 0, 0);
    }

#pragma unroll
  for (int mt = 0; mt < 4; ++mt)
#pragma unroll
    for (int i = 0; i < 4; ++i) {
      const float inv = 1.f / (__shfl(qn[mt], quad * 4 + i, 64) + EPS);
      const size_t roff = base + (size_t)(mt * 16 + quad * 4 + i) * 64;
#pragma unroll
      for (int nt = 0; nt < 4; ++nt)
        Ab[roff + nt * 16 + l15] = f2bfbits(acc[mt][nt][i] * inv);
    }
}

// ---------------------------------------------------------------------------
// Buffers (ws = 130 MB):
//  ws   @0      : Q -> A (in place)  [K is never materialized]
//  ws   @64MB   : V ; first 8MB reused for Wo^T after attn
//  ws   @128MB  : ksum (fp32 8192x64, 2MB) — written by gemm_kv epilogue
//  d_out@0      : Xb (bf16 8192x1024, 16MB)       — dead before gemm_out writes
//  d_out@16MB   : WtKV (bf16 8192x1024, 16MB)     — then WqT (8MB)
// ---------------------------------------------------------------------------
extern "C" void kernel_launch(void* const* d_in, const int* in_sizes, int n_in,
                              void* d_out, int out_size, void* d_ws, size_t ws_size,
                              hipStream_t stream)
{
  const float* x  = (const float*)d_in[0];
  const float* Wq = (const float*)d_in[1];
  const float* Wk = (const float*)d_in[2];
  const float* Wv = (const float*)d_in[3];
  const float* Wo = (const float*)d_in[4];
  const float* bo = (const float*)d_in[5];
  float* out = (float*)d_out;

  uint8_t* ws = (uint8_t*)d_ws;
  const size_t HALF = (size_t)M_TOK * INNER * sizeof(bf16);  // 64 MB
  unsigned short* KQA = (unsigned short*)ws;            // Q -> A
  unsigned short* Vb  = (unsigned short*)(ws + HALF);   // V ; then Wo^T
  float* ks           = (float*)(ws + 2 * HALF);

  unsigned short* Xb   = (unsigned short*)d_out;                           // 16 MB
  unsigned short* WtKV = (unsigned short*)((uint8_t*)d_out + (16u << 20)); // 16 MB
  unsigned short* WqT  = WtKV;   // reused after gemm_kv
  unsigned short* Wot  = Vb;     // Wo^T over dead V (after attn)

  const dim3 blk(256);
  const dim3 blk512(512);

  // fused prep: castx (8192 blocks) + Wk^T dh-major (4096) + Wv^T (4096)
  prep_kernel<<<dim3(16384), blk, 0, stream>>>(x, Xb, Wk, Wv, WtKV);

  // fused K+V projection: K-blocks reduce straight to ksum (no K write),
  // V-blocks write V.  256^2 slip-pipelined (R5-verified core).
  gemm256<0, 1><<<dim3(2 * INNER / 256, M_TOK / 256), blk512, 0, stream>>>(
      Xb, WtKV, nullptr, Vb, ks, 2 * INNER, DIM);

  tcast_kernel<<<dim3(INNER / 32, DIM / 32), blk, 0, stream>>>(
      Wq, WqT, DIM, INNER);

  // Q projection: relu * QSCALE -> KQA
  gemm256<2, 0><<<dim3(INNER / 256, M_TOK / 256), blk512, 0, stream>>>(
      Xb, WqT, KQA, nullptr, nullptr, INNER, DIM);

  attn_mfma<<<dim3(M_TOK / 4), blk, 0, stream>>>(KQA, Vb, ks, KQA);  // A in place

  tcast_kernel<<<dim3(DIM / 32, INNER / 32), blk, 0, stream>>>(
      Wo, Wot, INNER, DIM);  // over dead V

  // output GEMM: 128x128 tile (R0-verified drain structure), fp32 + bias
  gemm_out128<<<dim3(DIM / 128, M_TOK / 128), blk, 0, stream>>>(
      KQA, Wot, bo, out, DIM, INNER);
}